// Round 1
// baseline (1328.414 us; speedup 1.0000x reference)
//
#include <hip/hip_runtime.h>
#include <stdint.h>
#include <stddef.h>

// ---------------- problem constants ----------------
constexpr int BB = 4, SS = 2048, DD = 512, HH = 8, LL = 4;
constexpr int NTOK = BB * SS;          // 8192 tokens
constexpr float BN_EPS = 1e-3f;

using bh = __bf16;
typedef __bf16 bf16x8 __attribute__((ext_vector_type(8)));
typedef float  f32x4  __attribute__((ext_vector_type(4)));

#define DEV __device__ __forceinline__

DEV void gload_lds16(const void* g, void* l) {
    __builtin_amdgcn_global_load_lds(
        (const __attribute__((address_space(1))) void*)g,
        (__attribute__((address_space(3))) void*)l, 16, 0, 0);
}

// ---------------- weight prep: f32 [L][512][512] -> bf16 transposed [L][512][512] ----------------
__global__ void wprep(const float* __restrict__ in, bh* __restrict__ out) {
    __shared__ float t[32][33];
    const float* ip = in + (size_t)blockIdx.z * DD * DD;
    bh* op = out + (size_t)blockIdx.z * DD * DD;
    const int r0 = blockIdx.y * 32, c0 = blockIdx.x * 32;
    const int tx = threadIdx.x, ty = threadIdx.y;   // 32 x 8
    #pragma unroll
    for (int i = ty; i < 32; i += 8) t[i][tx] = ip[(size_t)(r0 + i) * DD + c0 + tx];
    __syncthreads();
    #pragma unroll
    for (int i = ty; i < 32; i += 8) op[(size_t)(c0 + i) * DD + r0 + tx] = (bh)t[tx][i];
}

// ---------------- embedding + positional; writes f32 x and bf16 copy ----------------
__global__ void embed_k(const int* __restrict__ seq, const float* __restrict__ emb,
                        const float* __restrict__ pos, float* __restrict__ x,
                        bh* __restrict__ xb) {
    const int m = blockIdx.x;                // 0..8191
    const int s = m & (SS - 1);
    const int tok = seq[m];
    const int d = threadIdx.x * 4;           // 128 threads * 4 floats
    const float4 e  = *(const float4*)(emb + (size_t)tok * DD + d);
    const float4 pz = *(const float4*)(pos + (size_t)s * DD + d);
    float4 v;
    v.x = e.x + pz.x; v.y = e.y + pz.y; v.z = e.z + pz.z; v.w = e.w + pz.w;
    *(float4*)(x + (size_t)m * DD + d) = v;
    union { bh h[4]; uint64_t u; } pk;
    pk.h[0] = (bh)v.x; pk.h[1] = (bh)v.y; pk.h[2] = (bh)v.z; pk.h[3] = (bh)v.w;
    *(uint64_t*)(xb + (size_t)m * DD + d) = pk.u;
}

// ---------------- V transpose: [B*S,512] (head slice) -> VT [B,H,64,S] ----------------
__global__ void vtrans(const bh* __restrict__ V, bh* __restrict__ VT) {
    __shared__ bh t[64][65];
    const int s0 = blockIdx.x * 64, h = blockIdx.y, b = blockIdx.z;
    const int tx = threadIdx.x, ty = threadIdx.y;   // 64 x 4
    #pragma unroll
    for (int i = ty; i < 64; i += 4)
        t[i][tx] = V[(size_t)(b * SS + s0 + i) * DD + h * 64 + tx];
    __syncthreads();
    #pragma unroll
    for (int i = ty; i < 64; i += 4)
        VT[((size_t)((b * HH + h) * 64) + i) * SS + s0 + tx] = t[tx][i];
}

// ---------------- GEMM: C[M=8192, N=512] = A[M,512] @ Bt[N,512]^T  (+ fused epilogues) ----------
// EP 0: outb = bf16(acc + bias)
// EP 1: t = res + acc + bias; s = BN(t); res = s (f32); outb = bf16(s)
// EP 2: outb = bf16(relu(acc + bias))
template <int EP>
__global__ __launch_bounds__(256)
void gemm_bt(const bh* __restrict__ A, const bh* __restrict__ Bt,
             const float* __restrict__ bias, bh* __restrict__ outb,
             float* __restrict__ res,
             const float* __restrict__ gamma, const float* __restrict__ beta,
             const float* __restrict__ mean, const float* __restrict__ var) {
    constexpr int BM = 128, BN = 64, BK = 64;
    __shared__ __align__(16) bh As[BM * BK];   // 16 KB, [row][64] xor-swizzled by 16B unit
    __shared__ __align__(16) bh Bs[BN * BK];   // 8 KB

    const int tid = threadIdx.x;
    const int w = tid >> 6, lane = tid & 63;
    const int l15 = lane & 15, l4 = lane >> 4;
    const int bm = (int)blockIdx.x >> 3;      // 64 tiles along M
    const int bn = (int)blockIdx.x & 7;       // 8 tiles along N
    const int m0 = bm * BM, n0 = bn * BN;
    const int wr = w >> 1, wc = w & 1;        // wave tile: 64 x 32

    f32x4 acc[4][2] = {};

    const int sr = lane >> 3;                 // row within 8-row stripe
    const int cb = lane & 7;                  // 16B column unit

    for (int kk = 0; kk < DD; kk += BK) {
        // stage A tile (16 x 1KB instructions), inverse-swizzled global source
        #pragma unroll
        for (int i = 0; i < 4; ++i) {
            const int idx = w * 4 + i;
            const int r = idx * 8 + sr;
            gload_lds16(A + (size_t)(m0 + r) * DD + kk + 8 * (cb ^ (r & 7)), As + idx * 512);
        }
        #pragma unroll
        for (int i = 0; i < 2; ++i) {
            const int idx = w * 2 + i;
            const int r = idx * 8 + sr;
            gload_lds16(Bt + (size_t)(n0 + r) * DD + kk + 8 * (cb ^ (r & 7)), Bs + idx * 512);
        }
        __syncthreads();

        const char* Ab = (const char*)As;
        const char* Bb = (const char*)Bs;
        #pragma unroll
        for (int ks = 0; ks < 2; ++ks) {
            bf16x8 af[4], bfr[2];
            const int cby = ks * 64 + l4 * 16;
            #pragma unroll
            for (int mf = 0; mf < 4; ++mf) {
                const int row = wr * 64 + mf * 16 + l15;
                af[mf] = *(const bf16x8*)(Ab + row * 128 + (cby ^ ((row & 7) << 4)));
            }
            #pragma unroll
            for (int nf = 0; nf < 2; ++nf) {
                const int row = wc * 32 + nf * 16 + l15;
                bfr[nf] = *(const bf16x8*)(Bb + row * 128 + (cby ^ ((row & 7) << 4)));
            }
            #pragma unroll
            for (int mf = 0; mf < 4; ++mf)
                #pragma unroll
                for (int nf = 0; nf < 2; ++nf)
                    acc[mf][nf] = __builtin_amdgcn_mfma_f32_16x16x32_bf16(
                        af[mf], bfr[nf], acc[mf][nf], 0, 0, 0);
        }
        __syncthreads();
    }

    // epilogue: D layout col = l15, row = l4*4 + r
    #pragma unroll
    for (int nf = 0; nf < 2; ++nf) {
        const int n = n0 + wc * 32 + nf * 16 + l15;
        const float bi = bias[n];
        float g = 0.f, be = 0.f, mu = 0.f, iv = 0.f;
        if constexpr (EP == 1) {
            g = gamma[n]; be = beta[n]; mu = mean[n];
            iv = rsqrtf(var[n] + BN_EPS);
        }
        #pragma unroll
        for (int mf = 0; mf < 4; ++mf) {
            #pragma unroll
            for (int r = 0; r < 4; ++r) {
                const int m = m0 + wr * 64 + mf * 16 + l4 * 4 + r;
                const size_t off = (size_t)m * DD + n;
                const float v = acc[mf][nf][r] + bi;
                if constexpr (EP == 0) {
                    outb[off] = (bh)v;
                } else if constexpr (EP == 2) {
                    outb[off] = (bh)fmaxf(v, 0.f);
                } else {
                    const float t = res[off] + v;
                    const float s = (t - mu) * iv * g + be;
                    res[off] = s;
                    outb[off] = (bh)s;
                }
            }
        }
    }
}

// ---------------- flash attention ----------------
// Q,K: [B*S, 512] bf16 (head slice at h*64);  VT: [B,H,64,S];  mask: [B,S] (0/1 f32)
// O (ctx): [B*S, 512] bf16. Grid: qt(32) x h(8) x b(4) = 1024 blocks, 4 waves.
// Per wave: 16 q rows; loop 64-key tiles; mfma 16x16x32; online softmax.
__global__ __launch_bounds__(256)
void flash_attn(const bh* __restrict__ Q, const bh* __restrict__ K,
                const bh* __restrict__ VT, const float* __restrict__ mask,
                bh* __restrict__ O) {
    __shared__ __align__(16) bh Plds[4][16][72];   // wave-private stripes, stride 72
    const int tid = threadIdx.x;
    const int w = tid >> 6, lane = tid & 63;
    const int l15 = lane & 15, l4 = lane >> 4;
    const int qt = (int)blockIdx.x & 31;
    const int h  = ((int)blockIdx.x >> 5) & 7;
    const int b  = (int)blockIdx.x >> 8;

    const int q0 = qt * 64 + w * 16;

    // Q fragments (row = l15, k = ks*32 + l4*8)
    const bh* qp = Q + (size_t)(b * SS + q0 + l15) * DD + h * 64 + l4 * 8;
    const bf16x8 qf0 = *(const bf16x8*)qp;
    const bf16x8 qf1 = *(const bf16x8*)(qp + 32);

    f32x4 ctx[4] = {};
    float mrun[4] = {-1e30f, -1e30f, -1e30f, -1e30f};
    float lrun[4] = {};

    const bh* kbase = K + (size_t)b * SS * DD + h * 64 + l4 * 8;
    const bh* vbase = VT + ((size_t)((b * HH + h) * 64) + l15) * SS + l4 * 8;
    const float* mbase = mask + (size_t)b * SS;

    for (int kt = 0; kt < SS; kt += 64) {
        // ---- scores S[16q x 64k] = Q K^T ----
        f32x4 sc[4] = {};
        #pragma unroll
        for (int nf = 0; nf < 4; ++nf) {
            const bh* kp = kbase + (size_t)(kt + nf * 16 + l15) * DD;
            const bf16x8 kf0 = *(const bf16x8*)kp;
            const bf16x8 kf1 = *(const bf16x8*)(kp + 32);
            sc[nf] = __builtin_amdgcn_mfma_f32_16x16x32_bf16(qf0, kf0, sc[nf], 0, 0, 0);
            sc[nf] = __builtin_amdgcn_mfma_f32_16x16x32_bf16(qf1, kf1, sc[nf], 0, 0, 0);
        }
        // ---- scale + mask ----
        #pragma unroll
        for (int nf = 0; nf < 4; ++nf) {
            const float mv = mbase[kt + nf * 16 + l15];
            #pragma unroll
            for (int r = 0; r < 4; ++r)
                sc[nf][r] = (mv == 0.0f) ? -1e9f : sc[nf][r] * 0.125f;
        }
        // ---- row max (rows live at l4*4+r across the 16 l15 lanes) ----
        float tmax[4];
        #pragma unroll
        for (int r = 0; r < 4; ++r)
            tmax[r] = fmaxf(fmaxf(sc[0][r], sc[1][r]), fmaxf(sc[2][r], sc[3][r]));
        #pragma unroll
        for (int d = 1; d < 16; d <<= 1) {
            #pragma unroll
            for (int r = 0; r < 4; ++r)
                tmax[r] = fmaxf(tmax[r], __shfl_xor(tmax[r], d, 64));
        }
        float fac[4], ps[4];
        #pragma unroll
        for (int r = 0; r < 4; ++r) {
            const float mn = fmaxf(mrun[r], tmax[r]);
            fac[r] = __expf(mrun[r] - mn);
            mrun[r] = mn;
            ps[r] = 0.f;
        }
        // ---- P = exp(S - m), row sums ----
        #pragma unroll
        for (int nf = 0; nf < 4; ++nf) {
            #pragma unroll
            for (int r = 0; r < 4; ++r) {
                const float pv = __expf(sc[nf][r] - mrun[r]);
                sc[nf][r] = pv;
                ps[r] += pv;
            }
        }
        #pragma unroll
        for (int d = 1; d < 16; d <<= 1) {
            #pragma unroll
            for (int r = 0; r < 4; ++r)
                ps[r] += __shfl_xor(ps[r], d, 64);
        }
        #pragma unroll
        for (int r = 0; r < 4; ++r)
            lrun[r] = lrun[r] * fac[r] + ps[r];
        #pragma unroll
        for (int nf = 0; nf < 4; ++nf)
            #pragma unroll
            for (int r = 0; r < 4; ++r)
                ctx[nf][r] *= fac[r];
        // ---- P -> LDS (relayout to A-fragment order) ----
        #pragma unroll
        for (int nf = 0; nf < 4; ++nf)
            #pragma unroll
            for (int r = 0; r < 4; ++r)
                Plds[w][l4 * 4 + r][nf * 16 + l15] = (bh)sc[nf][r];
        const bf16x8 pa0 = *(const bf16x8*)&Plds[w][l15][l4 * 8];
        const bf16x8 pa1 = *(const bf16x8*)&Plds[w][l15][32 + l4 * 8];
        // ---- ctx += P @ V ----
        #pragma unroll
        for (int nf = 0; nf < 4; ++nf) {
            const bh* vp = vbase + (size_t)nf * 16 * SS + kt;
            const bf16x8 vf0 = *(const bf16x8*)vp;
            const bf16x8 vf1 = *(const bf16x8*)(vp + 32);
            ctx[nf] = __builtin_amdgcn_mfma_f32_16x16x32_bf16(pa0, vf0, ctx[nf], 0, 0, 0);
            ctx[nf] = __builtin_amdgcn_mfma_f32_16x16x32_bf16(pa1, vf1, ctx[nf], 0, 0, 0);
        }
    }
    // ---- normalize and store ----
    #pragma unroll
    for (int r = 0; r < 4; ++r) lrun[r] = 1.0f / lrun[r];
    #pragma unroll
    for (int nf = 0; nf < 4; ++nf)
        #pragma unroll
        for (int r = 0; r < 4; ++r)
            O[(size_t)(b * SS + q0 + l4 * 4 + r) * DD + h * 64 + nf * 16 + l15] =
                (bh)(ctx[nf][r] * lrun[r]);
}

// ---------------- host launch ----------------
extern "C" void kernel_launch(void* const* d_in, const int* in_sizes, int n_in,
                              void* d_out, int out_size, void* d_ws, size_t ws_size,
                              hipStream_t stream) {
    const int*   seq  = (const int*)  d_in[0];
    const float* mask = (const float*)d_in[1];
    const float* pos  = (const float*)d_in[2];
    const float* emb  = (const float*)d_in[3];
    const float* wq = (const float*)d_in[4];  const float* bq = (const float*)d_in[5];
    const float* wk = (const float*)d_in[6];  const float* bk = (const float*)d_in[7];
    const float* wv = (const float*)d_in[8];  const float* bv = (const float*)d_in[9];
    const float* wo = (const float*)d_in[10]; const float* bo = (const float*)d_in[11];
    const float* ag = (const float*)d_in[12]; const float* ab = (const float*)d_in[13];
    const float* am = (const float*)d_in[14]; const float* av = (const float*)d_in[15];
    const float* d1w = (const float*)d_in[16]; const float* d1b = (const float*)d_in[17];
    const float* d2w = (const float*)d_in[18]; const float* d2b = (const float*)d_in[19];
    const float* fg = (const float*)d_in[20]; const float* fb = (const float*)d_in[21];
    const float* fm = (const float*)d_in[22]; const float* fv = (const float*)d_in[23];

    float* X = (float*)d_out;

    char* p = (char*)d_ws;
    auto take = [&](size_t n) { char* q = p; p += (n + 255) & ~(size_t)255; return q; };
    const size_t WE = (size_t)LL * DD * DD;
    bh* wqt = (bh*)take(WE * 2); bh* wkt = (bh*)take(WE * 2);
    bh* wvt = (bh*)take(WE * 2); bh* wot = (bh*)take(WE * 2);
    bh* w1t = (bh*)take(WE * 2); bh* w2t = (bh*)take(WE * 2);
    const size_t AE = (size_t)NTOK * DD;
    bh* xb   = (bh*)take(AE * 2);
    bh* qb   = (bh*)take(AE * 2);
    bh* kb   = (bh*)take(AE * 2);
    bh* ctxb = (bh*)take(AE * 2);
    bh* subb = (bh*)take(AE * 2);
    bh* h1b  = (bh*)take(AE * 2);
    bh* vT   = (bh*)take(AE * 2);
    bh* vtmp = h1b;   // reuse: v (pre-transpose) is dead before FFN1 writes h1b

    const dim3 wg(16, 16, LL), wb(32, 8);
    wprep<<<wg, wb, 0, stream>>>(wq,  wqt);
    wprep<<<wg, wb, 0, stream>>>(wk,  wkt);
    wprep<<<wg, wb, 0, stream>>>(wv,  wvt);
    wprep<<<wg, wb, 0, stream>>>(wo,  wot);
    wprep<<<wg, wb, 0, stream>>>(d1w, w1t);
    wprep<<<wg, wb, 0, stream>>>(d2w, w2t);

    embed_k<<<dim3(NTOK), dim3(128), 0, stream>>>(seq, emb, pos, X, xb);

    for (int l = 0; l < LL; ++l) {
        const size_t wof = (size_t)l * DD * DD;
        const int    bof = l * DD;
        gemm_bt<0><<<dim3(512), dim3(256), 0, stream>>>(
            xb, wqt + wof, bq + bof, qb, nullptr, nullptr, nullptr, nullptr, nullptr);
        gemm_bt<0><<<dim3(512), dim3(256), 0, stream>>>(
            xb, wkt + wof, bk + bof, kb, nullptr, nullptr, nullptr, nullptr, nullptr);
        gemm_bt<0><<<dim3(512), dim3(256), 0, stream>>>(
            xb, wvt + wof, bv + bof, vtmp, nullptr, nullptr, nullptr, nullptr, nullptr);
        vtrans<<<dim3(SS / 64, HH, BB), dim3(64, 4), 0, stream>>>(vtmp, vT);
        flash_attn<<<dim3(1024), dim3(256), 0, stream>>>(qb, kb, vT, mask, ctxb);
        gemm_bt<1><<<dim3(512), dim3(256), 0, stream>>>(
            ctxb, wot + wof, bo + bof, subb, X, ag + bof, ab + bof, am + bof, av + bof);
        gemm_bt<2><<<dim3(512), dim3(256), 0, stream>>>(
            subb, w1t + wof, d1b + bof, h1b, nullptr, nullptr, nullptr, nullptr, nullptr);
        gemm_bt<1><<<dim3(512), dim3(256), 0, stream>>>(
            h1b, w2t + wof, d2b + bof, xb, X, fg + bof, fb + bof, fm + bof, fv + bof);
    }
}

// Round 2
// 713.357 us; speedup vs baseline: 1.8622x; 1.8622x over previous
//
#include <hip/hip_runtime.h>
#include <stdint.h>
#include <stddef.h>

// ---------------- problem constants ----------------
constexpr int BB = 4, SS = 2048, DD = 512, HH = 8, LL = 4;
constexpr int NTOK = BB * SS;          // 8192 tokens
constexpr float BN_EPS = 1e-3f;

using bh = __bf16;
typedef __bf16 bf16x8 __attribute__((ext_vector_type(8)));
typedef float  f32x4  __attribute__((ext_vector_type(4)));

#define DEV __device__ __forceinline__

DEV void gload_lds16(const void* g, void* l) {
    __builtin_amdgcn_global_load_lds(
        (const __attribute__((address_space(1))) void*)g,
        (__attribute__((address_space(3))) void*)l, 16, 0, 0);
}

// ---------------- weight prep: f32 [L][512][512] -> bf16 transposed [L][512][512] ----------------
__global__ void wprep(const float* __restrict__ in, bh* __restrict__ out) {
    __shared__ float t[32][33];
    const float* ip = in + (size_t)blockIdx.z * DD * DD;
    bh* op = out + (size_t)blockIdx.z * DD * DD;
    const int r0 = blockIdx.y * 32, c0 = blockIdx.x * 32;
    const int tx = threadIdx.x, ty = threadIdx.y;   // 32 x 8
    #pragma unroll
    for (int i = ty; i < 32; i += 8) t[i][tx] = ip[(size_t)(r0 + i) * DD + c0 + tx];
    __syncthreads();
    #pragma unroll
    for (int i = ty; i < 32; i += 8) op[(size_t)(c0 + i) * DD + r0 + tx] = (bh)t[tx][i];
}

// ---------------- embedding + positional; writes f32 x and bf16 copy ----------------
__global__ void embed_k(const int* __restrict__ seq, const float* __restrict__ emb,
                        const float* __restrict__ pos, float* __restrict__ x,
                        bh* __restrict__ xb) {
    const int m = blockIdx.x;                // 0..8191
    const int s = m & (SS - 1);
    const int tok = seq[m];
    const int d = threadIdx.x * 4;           // 128 threads * 4 floats
    const float4 e  = *(const float4*)(emb + (size_t)tok * DD + d);
    const float4 pz = *(const float4*)(pos + (size_t)s * DD + d);
    float4 v;
    v.x = e.x + pz.x; v.y = e.y + pz.y; v.z = e.z + pz.z; v.w = e.w + pz.w;
    *(float4*)(x + (size_t)m * DD + d) = v;
    union { bh h[4]; uint64_t u; } pk;
    pk.h[0] = (bh)v.x; pk.h[1] = (bh)v.y; pk.h[2] = (bh)v.z; pk.h[3] = (bh)v.w;
    *(uint64_t*)(xb + (size_t)m * DD + d) = pk.u;
}

// ---------------- V transpose: [B*S,512] (head slice) -> VT [B,H,64,S] ----------------
__global__ void vtrans(const bh* __restrict__ V, bh* __restrict__ VT) {
    __shared__ bh t[64][65];
    const int s0 = blockIdx.x * 64, h = blockIdx.y, b = blockIdx.z;
    const int tx = threadIdx.x, ty = threadIdx.y;   // 64 x 4
    #pragma unroll
    for (int i = ty; i < 64; i += 4)
        t[i][tx] = V[(size_t)(b * SS + s0 + i) * DD + h * 64 + tx];
    __syncthreads();
    #pragma unroll
    for (int i = ty; i < 64; i += 4)
        VT[((size_t)((b * HH + h) * 64) + i) * SS + s0 + tx] = t[tx][i];
}

// ---------------- GEMM: C[M=8192, N=512] = A[M,512] @ Bt[N,512]^T  (+ fused epilogues) ----------
// EP 0: outb = bf16(acc + bias)
// EP 1: t = res + acc + bias; s = BN(t); res = s (f32); outb = bf16(s)
// EP 2: outb = bf16(relu(acc + bias))
template <int EP>
__global__ __launch_bounds__(256)
void gemm_bt(const bh* __restrict__ A, const bh* __restrict__ Bt,
             const float* __restrict__ bias, bh* __restrict__ outb,
             float* __restrict__ res,
             const float* __restrict__ gamma, const float* __restrict__ beta,
             const float* __restrict__ mean, const float* __restrict__ var) {
    constexpr int BM = 128, BN = 64, BK = 64;
    __shared__ __align__(16) bh As[BM * BK];   // 16 KB, [row][64] xor-swizzled by 16B unit
    __shared__ __align__(16) bh Bs[BN * BK];   // 8 KB

    const int tid = threadIdx.x;
    const int w = tid >> 6, lane = tid & 63;
    const int l15 = lane & 15, l4 = lane >> 4;
    const int bm = (int)blockIdx.x >> 3;      // 64 tiles along M
    const int bn = (int)blockIdx.x & 7;       // 8 tiles along N
    const int m0 = bm * BM, n0 = bn * BN;
    const int wr = w >> 1, wc = w & 1;        // wave tile: 64 x 32

    f32x4 acc[4][2] = {};

    const int sr = lane >> 3;                 // row within 8-row stripe
    const int cb = lane & 7;                  // 16B column unit

    for (int kk = 0; kk < DD; kk += BK) {
        #pragma unroll
        for (int i = 0; i < 4; ++i) {
            const int idx = w * 4 + i;
            const int r = idx * 8 + sr;
            gload_lds16(A + (size_t)(m0 + r) * DD + kk + 8 * (cb ^ (r & 7)), As + idx * 512);
        }
        #pragma unroll
        for (int i = 0; i < 2; ++i) {
            const int idx = w * 2 + i;
            const int r = idx * 8 + sr;
            gload_lds16(Bt + (size_t)(n0 + r) * DD + kk + 8 * (cb ^ (r & 7)), Bs + idx * 512);
        }
        __syncthreads();

        const char* Ab = (const char*)As;
        const char* Bb = (const char*)Bs;
        #pragma unroll
        for (int ks = 0; ks < 2; ++ks) {
            bf16x8 af[4], bfr[2];
            const int cby = ks * 64 + l4 * 16;
            #pragma unroll
            for (int mf = 0; mf < 4; ++mf) {
                const int row = wr * 64 + mf * 16 + l15;
                af[mf] = *(const bf16x8*)(Ab + row * 128 + (cby ^ ((row & 7) << 4)));
            }
            #pragma unroll
            for (int nf = 0; nf < 2; ++nf) {
                const int row = wc * 32 + nf * 16 + l15;
                bfr[nf] = *(const bf16x8*)(Bb + row * 128 + (cby ^ ((row & 7) << 4)));
            }
            #pragma unroll
            for (int mf = 0; mf < 4; ++mf)
                #pragma unroll
                for (int nf = 0; nf < 2; ++nf)
                    acc[mf][nf] = __builtin_amdgcn_mfma_f32_16x16x32_bf16(
                        af[mf], bfr[nf], acc[mf][nf], 0, 0, 0);
        }
        __syncthreads();
    }

    // epilogue: D layout col = l15, row = l4*4 + r
    #pragma unroll
    for (int nf = 0; nf < 2; ++nf) {
        const int n = n0 + wc * 32 + nf * 16 + l15;
        const float bi = bias[n];
        float g = 0.f, be = 0.f, mu = 0.f, iv = 0.f;
        if constexpr (EP == 1) {
            g = gamma[n]; be = beta[n]; mu = mean[n];
            iv = rsqrtf(var[n] + BN_EPS);
        }
        #pragma unroll
        for (int mf = 0; mf < 4; ++mf) {
            #pragma unroll
            for (int r = 0; r < 4; ++r) {
                const int m = m0 + wr * 64 + mf * 16 + l4 * 4 + r;
                const size_t off = (size_t)m * DD + n;
                const float v = acc[mf][nf][r] + bi;
                if constexpr (EP == 0) {
                    outb[off] = (bh)v;
                } else if constexpr (EP == 2) {
                    outb[off] = (bh)fmaxf(v, 0.f);
                } else {
                    const float t = res[off] + v;
                    const float s = (t - mu) * iv * g + be;
                    res[off] = s;
                    outb[off] = (bh)s;
                }
            }
        }
    }
}

// ---------------- flash attention v2: LDS-staged K/V, swapped MFMA, in-reg softmax ----------
// Q,K: [B*S,512] bf16 (head slice at h*64); VT: [B,H,64,S]; mask: [B,S]; O: [B*S,512] bf16.
// 512 blocks (XCD-pinned groups), 4 waves, 32 q-rows/wave (128 q/block), KVB=64 key tiles.
// Swapped layout: scores D[key][q] with q = lane&15 -> softmax reduce is in-register + 2 shfl.
__global__ __launch_bounds__(256)
void flash_attn(const bh* __restrict__ Q, const bh* __restrict__ K,
                const bh* __restrict__ VT, const float* __restrict__ mask,
                bh* __restrict__ O) {
    constexpr int KVB = 64;
    constexpr int NT = SS / KVB;   // 32
    __shared__ __align__(16) bh Ks[2][KVB * 64];   // 16 KB  [key][dk], xor-swizzled
    __shared__ __align__(16) bh Vs[2][64 * KVB];   // 16 KB  [dk][key], xor-swizzled
    __shared__ __align__(16) bh Plds[4][32][64];   // 16 KB  wave-private [q][key], xor-swizzled

    const int tid = threadIdx.x;
    const int w = tid >> 6, lane = tid & 63;
    const int l15 = lane & 15, l4 = lane >> 4;

    // XCD-pinning swizzle: all 16 q-tiles of one (b,h) group land on one XCD
    const int i = (int)blockIdx.x;
    const int xcd = i & 7, j = i >> 3;         // j 0..63
    const int g = xcd * 4 + (j >> 4);          // group (b,h) 0..31
    const int qt = j & 15;
    const int h = g & 7, b = g >> 3;

    const int q0 = qt * 128 + w * 32;

    // Q fragments (B-operand): lane holds Q[q=mf*16+l15][dk = ks*32 + l4*8 ..]
    bf16x8 qf[2][2];
    #pragma unroll
    for (int mf = 0; mf < 2; ++mf) {
        const bh* qp = Q + (size_t)(b * SS + q0 + mf * 16 + l15) * DD + h * 64 + l4 * 8;
        qf[mf][0] = *(const bf16x8*)qp;
        qf[mf][1] = *(const bf16x8*)(qp + 32);
    }

    f32x4 ctx[2][4] = {};
    float mrun[2] = {-1e30f, -1e30f};
    float lrun[2] = {0.f, 0.f};

    const float* mbase = mask + (size_t)b * SS;
    const int sr = lane >> 3;                  // row-within-8 for staging
    const int cbx = (lane & 7) ^ sr;           // inverse-swizzled 16B column unit
    const bh* kgbase = K + (size_t)b * SS * DD + h * 64 + 8 * cbx;
    const bh* vgbase = VT + (size_t)((b * HH + h) * 64) * SS + 8 * cbx;

    auto stage = [&](int buf, int kt) {
        #pragma unroll
        for (int ii = 0; ii < 2; ++ii) {
            const int idx = w * 2 + ii;        // 0..7 covers 64 rows
            const int r = idx * 8 + sr;
            gload_lds16(kgbase + (size_t)(kt + r) * DD, &Ks[buf][idx * 512]);
        }
        #pragma unroll
        for (int ii = 0; ii < 2; ++ii) {
            const int idx = w * 2 + ii;
            const int r = idx * 8 + sr;
            gload_lds16(vgbase + (size_t)r * SS + kt, &Vs[buf][idx * 512]);
        }
    };

    stage(0, 0);
    __syncthreads();

    for (int t = 0; t < NT; ++t) {
        const int buf = t & 1;
        const int kt = t * KVB;
        if (t + 1 < NT) stage(buf ^ 1, kt + KVB);

        // mask for keys this lane owns: key = nf*16 + l4*4 + r
        float4 mv4[4];
        #pragma unroll
        for (int nf = 0; nf < 4; ++nf)
            mv4[nf] = *(const float4*)(mbase + kt + nf * 16 + l4 * 4);

        // ---- QK^T (swapped): sc[mf][nf] = mfma(K_frag, Q_frag) -> D[key][q] ----
        f32x4 sc[2][4] = {};
        const char* Kb = (const char*)Ks[buf];
        #pragma unroll
        for (int ks = 0; ks < 2; ++ks) {
            bf16x8 kf[4];
            #pragma unroll
            for (int nf = 0; nf < 4; ++nf) {
                const int row = nf * 16 + l15;
                kf[nf] = *(const bf16x8*)(Kb + row * 128 +
                          ((ks * 64 + l4 * 16) ^ ((row & 7) << 4)));
            }
            __builtin_amdgcn_s_setprio(1);
            #pragma unroll
            for (int mf = 0; mf < 2; ++mf)
                #pragma unroll
                for (int nf = 0; nf < 4; ++nf)
                    sc[mf][nf] = __builtin_amdgcn_mfma_f32_16x16x32_bf16(
                        kf[nf], qf[mf][ks], sc[mf][nf], 0, 0, 0);
            __builtin_amdgcn_s_setprio(0);
        }

        // ---- online softmax: q = mf*16+l15 (lane-local rows) ----
        #pragma unroll
        for (int mf = 0; mf < 2; ++mf) {
            const int qrow = mf * 16 + l15;
            #pragma unroll
            for (int nf = 0; nf < 4; ++nf) {
                const float* mvp = (const float*)&mv4[nf];
                #pragma unroll
                for (int r = 0; r < 4; ++r) {
                    const float s = sc[mf][nf][r];
                    sc[mf][nf][r] = (mvp[r] == 0.0f) ? -1e9f : s * 0.125f;
                }
            }
            float tm = sc[mf][0][0];
            #pragma unroll
            for (int nf = 0; nf < 4; ++nf)
                #pragma unroll
                for (int r = 0; r < 4; ++r)
                    tm = fmaxf(tm, sc[mf][nf][r]);
            tm = fmaxf(tm, __shfl_xor(tm, 16, 64));
            tm = fmaxf(tm, __shfl_xor(tm, 32, 64));
            const float mn = fmaxf(mrun[mf], tm);
            const float fac = __expf(mrun[mf] - mn);
            mrun[mf] = mn;
            float psum = 0.f;
            #pragma unroll
            for (int nf = 0; nf < 4; ++nf) {
                union { bh h4[4]; uint64_t u; } pk;
                #pragma unroll
                for (int r = 0; r < 4; ++r) {
                    const float p = __expf(sc[mf][nf][r] - mn);
                    psum += p;
                    pk.h4[r] = (bh)p;
                }
                *(uint64_t*)((char*)&Plds[w][qrow][0] +
                             ((nf * 32 + l4 * 8) ^ ((qrow & 7) << 4))) = pk.u;
            }
            psum += __shfl_xor(psum, 16, 64);
            psum += __shfl_xor(psum, 32, 64);
            lrun[mf] = lrun[mf] * fac + psum;
            #pragma unroll
            for (int nf = 0; nf < 4; ++nf)
                #pragma unroll
                for (int r = 0; r < 4; ++r)
                    ctx[mf][nf][r] *= fac;
        }

        // ---- PV (swapped): ctx[mf][nf] = mfma(V_frag, P_frag) -> D[dk][q] ----
        const char* Vb = (const char*)Vs[buf];
        #pragma unroll
        for (int ks = 0; ks < 2; ++ks) {
            bf16x8 vf[4];
            #pragma unroll
            for (int nf = 0; nf < 4; ++nf) {
                const int row = nf * 16 + l15;
                vf[nf] = *(const bf16x8*)(Vb + row * 128 +
                          ((ks * 64 + l4 * 16) ^ ((row & 7) << 4)));
            }
            bf16x8 pa[2];
            #pragma unroll
            for (int mf = 0; mf < 2; ++mf) {
                const int qrow = mf * 16 + l15;
                pa[mf] = *(const bf16x8*)((const char*)&Plds[w][qrow][0] +
                          ((ks * 64 + l4 * 16) ^ ((qrow & 7) << 4)));
            }
            __builtin_amdgcn_s_setprio(1);
            #pragma unroll
            for (int mf = 0; mf < 2; ++mf)
                #pragma unroll
                for (int nf = 0; nf < 4; ++nf)
                    ctx[mf][nf] = __builtin_amdgcn_mfma_f32_16x16x32_bf16(
                        vf[nf], pa[mf], ctx[mf][nf], 0, 0, 0);
            __builtin_amdgcn_s_setprio(0);
        }
        __syncthreads();
    }

    // ---- epilogue: q = mf*16+l15, dk = nf*16 + l4*4 + r  (8B packed stores) ----
    #pragma unroll
    for (int mf = 0; mf < 2; ++mf) {
        const float linv = 1.0f / lrun[mf];
        #pragma unroll
        for (int nf = 0; nf < 4; ++nf) {
            union { bh h4[4]; uint64_t u; } pk;
            #pragma unroll
            for (int r = 0; r < 4; ++r)
                pk.h4[r] = (bh)(ctx[mf][nf][r] * linv);
            *(uint64_t*)(O + (size_t)(b * SS + q0 + mf * 16 + l15) * DD +
                         h * 64 + nf * 16 + l4 * 4) = pk.u;
        }
    }
}

// ---------------- host launch ----------------
extern "C" void kernel_launch(void* const* d_in, const int* in_sizes, int n_in,
                              void* d_out, int out_size, void* d_ws, size_t ws_size,
                              hipStream_t stream) {
    const int*   seq  = (const int*)  d_in[0];
    const float* mask = (const float*)d_in[1];
    const float* pos  = (const float*)d_in[2];
    const float* emb  = (const float*)d_in[3];
    const float* wq = (const float*)d_in[4];  const float* bq = (const float*)d_in[5];
    const float* wk = (const float*)d_in[6];  const float* bk = (const float*)d_in[7];
    const float* wv = (const float*)d_in[8];  const float* bv = (const float*)d_in[9];
    const float* wo = (const float*)d_in[10]; const float* bo = (const float*)d_in[11];
    const float* ag = (const float*)d_in[12]; const float* ab = (const float*)d_in[13];
    const float* am = (const float*)d_in[14]; const float* av = (const float*)d_in[15];
    const float* d1w = (const float*)d_in[16]; const float* d1b = (const float*)d_in[17];
    const float* d2w = (const float*)d_in[18]; const float* d2b = (const float*)d_in[19];
    const float* fg = (const float*)d_in[20]; const float* fb = (const float*)d_in[21];
    const float* fm = (const float*)d_in[22]; const float* fv = (const float*)d_in[23];

    float* X = (float*)d_out;

    char* p = (char*)d_ws;
    auto take = [&](size_t n) { char* q = p; p += (n + 255) & ~(size_t)255; return q; };
    const size_t WE = (size_t)LL * DD * DD;
    bh* wqt = (bh*)take(WE * 2); bh* wkt = (bh*)take(WE * 2);
    bh* wvt = (bh*)take(WE * 2); bh* wot = (bh*)take(WE * 2);
    bh* w1t = (bh*)take(WE * 2); bh* w2t = (bh*)take(WE * 2);
    const size_t AE = (size_t)NTOK * DD;
    bh* xb   = (bh*)take(AE * 2);
    bh* qb   = (bh*)take(AE * 2);
    bh* kb   = (bh*)take(AE * 2);
    bh* ctxb = (bh*)take(AE * 2);
    bh* subb = (bh*)take(AE * 2);
    bh* h1b  = (bh*)take(AE * 2);
    bh* vT   = (bh*)take(AE * 2);
    bh* vtmp = h1b;   // reuse: v (pre-transpose) is dead before FFN1 writes h1b

    const dim3 wg(16, 16, LL), wb(32, 8);
    wprep<<<wg, wb, 0, stream>>>(wq,  wqt);
    wprep<<<wg, wb, 0, stream>>>(wk,  wkt);
    wprep<<<wg, wb, 0, stream>>>(wv,  wvt);
    wprep<<<wg, wb, 0, stream>>>(wo,  wot);
    wprep<<<wg, wb, 0, stream>>>(d1w, w1t);
    wprep<<<wg, wb, 0, stream>>>(d2w, w2t);

    embed_k<<<dim3(NTOK), dim3(128), 0, stream>>>(seq, emb, pos, X, xb);

    for (int l = 0; l < LL; ++l) {
        const size_t wof = (size_t)l * DD * DD;
        const int    bof = l * DD;
        gemm_bt<0><<<dim3(512), dim3(256), 0, stream>>>(
            xb, wqt + wof, bq + bof, qb, nullptr, nullptr, nullptr, nullptr, nullptr);
        gemm_bt<0><<<dim3(512), dim3(256), 0, stream>>>(
            xb, wkt + wof, bk + bof, kb, nullptr, nullptr, nullptr, nullptr, nullptr);
        gemm_bt<0><<<dim3(512), dim3(256), 0, stream>>>(
            xb, wvt + wof, bv + bof, vtmp, nullptr, nullptr, nullptr, nullptr, nullptr);
        vtrans<<<dim3(SS / 64, HH, BB), dim3(64, 4), 0, stream>>>(vtmp, vT);
        flash_attn<<<dim3(512), dim3(256), 0, stream>>>(qb, kb, vT, mask, ctxb);
        gemm_bt<1><<<dim3(512), dim3(256), 0, stream>>>(
            ctxb, wot + wof, bo + bof, subb, X, ag + bof, ab + bof, am + bof, av + bof);
        gemm_bt<2><<<dim3(512), dim3(256), 0, stream>>>(
            subb, w1t + wof, d1b + bof, h1b, nullptr, nullptr, nullptr, nullptr, nullptr);
        gemm_bt<1><<<dim3(512), dim3(256), 0, stream>>>(
            h1b, w2t + wof, d2b + bof, xb, X, fg + bof, fb + bof, fm + bof, fv + bof);
    }
}

// Round 3
// 570.767 us; speedup vs baseline: 2.3274x; 1.2498x over previous
//
#include <hip/hip_runtime.h>
#include <stdint.h>
#include <stddef.h>

// ---------------- problem constants ----------------
constexpr int BB = 4, SS = 2048, DD = 512, HH = 8, LL = 4;
constexpr int NTOK = BB * SS;          // 8192 tokens
constexpr float BN_EPS = 1e-3f;

using bh = __bf16;
typedef __bf16 bf16x8 __attribute__((ext_vector_type(8)));
typedef float  f32x4  __attribute__((ext_vector_type(4)));

#define DEV __device__ __forceinline__
#define WAITVM(n) asm volatile("s_waitcnt vmcnt(" #n ")" ::: "memory")
#define WAITLGKM0 asm volatile("s_waitcnt lgkmcnt(0)" ::: "memory")

DEV void gload_lds16(const void* g, void* l) {
    __builtin_amdgcn_global_load_lds(
        (const __attribute__((address_space(1))) void*)g,
        (__attribute__((address_space(3))) void*)l, 16, 0, 0);
}

// ---------------- weight prep: f32 [L][512][512] -> bf16 transposed [L][512][512] ----------------
__global__ void wprep(const float* __restrict__ in, bh* __restrict__ out) {
    __shared__ float t[32][33];
    const float* ip = in + (size_t)blockIdx.z * DD * DD;
    bh* op = out + (size_t)blockIdx.z * DD * DD;
    const int r0 = blockIdx.y * 32, c0 = blockIdx.x * 32;
    const int tx = threadIdx.x, ty = threadIdx.y;   // 32 x 8
    #pragma unroll
    for (int i = ty; i < 32; i += 8) t[i][tx] = ip[(size_t)(r0 + i) * DD + c0 + tx];
    __syncthreads();
    #pragma unroll
    for (int i = ty; i < 32; i += 8) op[(size_t)(c0 + i) * DD + r0 + tx] = (bh)t[tx][i];
}

// ---------------- embedding + positional; writes f32 x and bf16 copy ----------------
__global__ void embed_k(const int* __restrict__ seq, const float* __restrict__ emb,
                        const float* __restrict__ pos, float* __restrict__ x,
                        bh* __restrict__ xb) {
    const int m = blockIdx.x;                // 0..8191
    const int s = m & (SS - 1);
    const int tok = seq[m];
    const int d = threadIdx.x * 4;           // 128 threads * 4 floats
    const float4 e  = *(const float4*)(emb + (size_t)tok * DD + d);
    const float4 pz = *(const float4*)(pos + (size_t)s * DD + d);
    float4 v;
    v.x = e.x + pz.x; v.y = e.y + pz.y; v.z = e.z + pz.z; v.w = e.w + pz.w;
    *(float4*)(x + (size_t)m * DD + d) = v;
    union { bh h[4]; uint64_t u; } pk;
    pk.h[0] = (bh)v.x; pk.h[1] = (bh)v.y; pk.h[2] = (bh)v.z; pk.h[3] = (bh)v.w;
    *(uint64_t*)(xb + (size_t)m * DD + d) = pk.u;
}

// ---------------- V transpose: [B*S,512] (head slice) -> VT [B,H,64,S] ----------------
__global__ void vtrans(const bh* __restrict__ V, bh* __restrict__ VT) {
    __shared__ bh t[64][65];
    const int s0 = blockIdx.x * 64, h = blockIdx.y, b = blockIdx.z;
    const int tx = threadIdx.x, ty = threadIdx.y;   // 64 x 4
    #pragma unroll
    for (int i = ty; i < 64; i += 4)
        t[i][tx] = V[(size_t)(b * SS + s0 + i) * DD + h * 64 + tx];
    __syncthreads();
    #pragma unroll
    for (int i = ty; i < 64; i += 4)
        VT[((size_t)((b * HH + h) * 64) + i) * SS + s0 + tx] = t[tx][i];
}

// ---------------- GEMM: C[M=8192, N=512] = A[M,512] @ Bt[N,512]^T  (+ fused epilogues) ----------
// Double-buffered LDS, counted vmcnt (no vmcnt(0) drain in main loop), XCD-aware tile map.
// EP 0: outb = bf16(acc + bias)
// EP 1: t = res + acc + bias; s = BN(t); res = s (f32); outb = bf16(s)
// EP 2: outb = bf16(relu(acc + bias))
template <int EP>
__global__ __launch_bounds__(256, 2)
void gemm_bt(const bh* __restrict__ A, const bh* __restrict__ Bt,
             const float* __restrict__ bias, bh* __restrict__ outb,
             float* __restrict__ res,
             const float* __restrict__ gamma, const float* __restrict__ beta,
             const float* __restrict__ mean, const float* __restrict__ var) {
    constexpr int BM = 128, BN = 64, BK = 64, NKT = DD / BK;   // 8 k-tiles
    __shared__ __align__(16) bh As[2][BM * BK];   // 2 x 16 KB
    __shared__ __align__(16) bh Bs[2][BN * BK];   // 2 x 8 KB

    const int tid = threadIdx.x;
    const int w = tid >> 6, lane = tid & 63;
    const int l15 = lane & 15, l4 = lane >> 4;
    // XCD swizzle: XCD x owns bm in [x*8, x*8+8) -> A panels L2-resident per XCD
    const int i = (int)blockIdx.x;
    const int xcd = i & 7, j = i >> 3;        // j 0..63
    const int bm = xcd * 8 + (j >> 3);        // 0..63
    const int bn = j & 7;                     // 0..7
    const int m0 = bm * BM, n0 = bn * BN;
    const int wr = w >> 1, wc = w & 1;        // wave tile: 64 x 32

    f32x4 acc[4][2] = {};

    const int sr = lane >> 3;                 // row within 8-row stripe
    const int cbx = (lane & 7) ^ sr;          // inverse-swizzled 16B column unit

    auto stage = [&](int buf, int kk) {
        #pragma unroll
        for (int ii = 0; ii < 4; ++ii) {
            const int idx = w * 4 + ii;
            const int r = idx * 8 + sr;
            gload_lds16(A + (size_t)(m0 + r) * DD + kk + 8 * cbx, &As[buf][idx * 512]);
        }
        #pragma unroll
        for (int ii = 0; ii < 2; ++ii) {
            const int idx = w * 2 + ii;
            const int r = idx * 8 + sr;
            gload_lds16(Bt + (size_t)(n0 + r) * DD + kk + 8 * cbx, &Bs[buf][idx * 512]);
        }
    };

    stage(0, 0);
    stage(1, BK);

    for (int kt = 0; kt < NKT; ++kt) {
        const int buf = kt & 1;
        if (kt + 1 < NKT) { WAITVM(6); } else { WAITVM(0); }
        __builtin_amdgcn_s_barrier();

        const char* Ab = (const char*)&As[buf][0];
        const char* Bb = (const char*)&Bs[buf][0];
        #pragma unroll
        for (int ks = 0; ks < 2; ++ks) {
            bf16x8 af[4], bfr[2];
            const int cby = ks * 64 + l4 * 16;
            #pragma unroll
            for (int mf = 0; mf < 4; ++mf) {
                const int row = wr * 64 + mf * 16 + l15;
                af[mf] = *(const bf16x8*)(Ab + row * 128 + (cby ^ ((row & 7) << 4)));
            }
            #pragma unroll
            for (int nf = 0; nf < 2; ++nf) {
                const int row = wc * 32 + nf * 16 + l15;
                bfr[nf] = *(const bf16x8*)(Bb + row * 128 + (cby ^ ((row & 7) << 4)));
            }
            #pragma unroll
            for (int mf = 0; mf < 4; ++mf)
                #pragma unroll
                for (int nf = 0; nf < 2; ++nf)
                    acc[mf][nf] = __builtin_amdgcn_mfma_f32_16x16x32_bf16(
                        af[mf], bfr[nf], acc[mf][nf], 0, 0, 0);
        }
        WAITLGKM0;
        __builtin_amdgcn_s_barrier();
        if (kt + 2 < NKT) stage(buf, (kt + 2) * BK);
    }

    // epilogue: D layout col = l15, row = l4*4 + r
    #pragma unroll
    for (int nf = 0; nf < 2; ++nf) {
        const int n = n0 + wc * 32 + nf * 16 + l15;
        const float bi = bias[n];
        float g = 0.f, be = 0.f, mu = 0.f, iv = 0.f;
        if constexpr (EP == 1) {
            g = gamma[n]; be = beta[n]; mu = mean[n];
            iv = rsqrtf(var[n] + BN_EPS);
        }
        #pragma unroll
        for (int mf = 0; mf < 4; ++mf) {
            #pragma unroll
            for (int r = 0; r < 4; ++r) {
                const int m = m0 + wr * 64 + mf * 16 + l4 * 4 + r;
                const size_t off = (size_t)m * DD + n;
                const float v = acc[mf][nf][r] + bi;
                if constexpr (EP == 0) {
                    outb[off] = (bh)v;
                } else if constexpr (EP == 2) {
                    outb[off] = (bh)fmaxf(v, 0.f);
                } else {
                    const float t = res[off] + v;
                    const float s = (t - mu) * iv * g + be;
                    res[off] = s;
                    outb[off] = (bh)s;
                }
            }
        }
    }
}

// ---------------- flash attention v3 ----------------
// 512 blocks (XCD-pinned (b,h) groups), 8 waves x 16 q-rows = 128 q/block, KVB=64 tiles.
// Counted-vmcnt double-buffered K/V staging; additive log2-domain mask bias from LDS;
// defer-max online softmax (rescale branch rarely taken); swapped MFMA throughout.
__global__ __launch_bounds__(512, 4)
void flash_attn(const bh* __restrict__ Q, const bh* __restrict__ K,
                const bh* __restrict__ VT, const float* __restrict__ mask,
                bh* __restrict__ O) {
    constexpr int KVB = 64;
    constexpr int NT = SS / KVB;   // 32
    constexpr float CSC = 0.18033688f;      // 0.125 * log2(e)
    __shared__ __align__(16) bh Ks[2][KVB * 64];   // 16 KB  [key][dk], xor-swizzled
    __shared__ __align__(16) bh Vs[2][64 * KVB];   // 16 KB  [dk][key], xor-swizzled
    __shared__ __align__(16) bh Plds[8][16][64];   // 16 KB  wave-private [q][key], xor-swizzled
    __shared__ float mbias[SS];                    // 8 KB   additive mask bias (log2 domain)

    const int tid = threadIdx.x;
    const int w = tid >> 6, lane = tid & 63;
    const int l15 = lane & 15, l4 = lane >> 4;

    // XCD-pinning swizzle: all 16 q-tiles of one (b,h) group land on one XCD
    const int i = (int)blockIdx.x;
    const int xcd = i & 7, j = i >> 3;         // j 0..63
    const int g = xcd * 4 + (j >> 4);          // group (b,h) 0..31
    const int qt = j & 15;
    const int h = g & 7, b = g >> 3;

    const int q0 = qt * 128 + w * 16;

    // mask bias -> LDS (one pass: 512 threads x 4 floats = 2048)
    {
        const int s = tid * 4;
        const float4 mv = *(const float4*)(mask + (size_t)b * SS + s);
        float4 bz;
        bz.x = (mv.x == 0.f) ? -1e30f : 0.f;
        bz.y = (mv.y == 0.f) ? -1e30f : 0.f;
        bz.z = (mv.z == 0.f) ? -1e30f : 0.f;
        bz.w = (mv.w == 0.f) ? -1e30f : 0.f;
        *(float4*)&mbias[s] = bz;
    }

    // Q fragments (B-operand): lane holds Q[q = q0+l15][dk = ks*32 + l4*8 ..]
    const bh* qp = Q + (size_t)(b * SS + q0 + l15) * DD + h * 64 + l4 * 8;
    const bf16x8 qf0 = *(const bf16x8*)qp;
    const bf16x8 qf1 = *(const bf16x8*)(qp + 32);

    f32x4 ctx[4] = {};
    float m2 = -3e38f, lrun = 0.f;

    const int sr = lane >> 3;
    const int cbx = (lane & 7) ^ sr;           // inverse-swizzled 16B column unit
    const bh* kgbase = K + (size_t)b * SS * DD + h * 64 + 8 * cbx;
    const bh* vgbase = VT + (size_t)((b * HH + h) * 64) * SS + 8 * cbx;
    const int r8 = w * 8 + sr;                 // this lane's staging row 0..63

    auto stage = [&](int buf, int kt) {
        gload_lds16(kgbase + (size_t)(kt + r8) * DD, &Ks[buf][w * 512]);
        gload_lds16(vgbase + (size_t)r8 * SS + kt, &Vs[buf][w * 512]);
    };

    stage(0, 0);
    stage(1, KVB);
    __syncthreads();   // one-time full drain: stages 0,1 + mbias visible

    for (int t = 0; t < NT; ++t) {
        const int buf = t & 1;
        const int kt = t * KVB;
        if (t > 0) {
            if (t + 1 < NT) { WAITVM(2); } else { WAITVM(0); }
            __builtin_amdgcn_s_barrier();
        }

        // ---- QK^T (swapped): sc[nf] = mfma(K_frag, Q_frag) -> D[key][q=l15] ----
        f32x4 sc[4] = {};
        const char* Kb = (const char*)&Ks[buf][0];
        #pragma unroll
        for (int ks = 0; ks < 2; ++ks) {
            bf16x8 kf[4];
            #pragma unroll
            for (int nf = 0; nf < 4; ++nf) {
                const int row = nf * 16 + l15;
                kf[nf] = *(const bf16x8*)(Kb + row * 128 +
                          ((ks * 64 + l4 * 16) ^ ((row & 7) << 4)));
            }
            __builtin_amdgcn_s_setprio(1);
            #pragma unroll
            for (int nf = 0; nf < 4; ++nf)
                sc[nf] = __builtin_amdgcn_mfma_f32_16x16x32_bf16(
                    kf[nf], ks ? qf1 : qf0, sc[nf], 0, 0, 0);
            __builtin_amdgcn_s_setprio(0);
        }

        // ---- z = qk*c + bias (log2 domain); row max; defer-max ----
        float tm = -3e38f;
        #pragma unroll
        for (int nf = 0; nf < 4; ++nf) {
            const f32x4 mb4 = *(const f32x4*)&mbias[kt + nf * 16 + l4 * 4];
            #pragma unroll
            for (int r = 0; r < 4; ++r) {
                const float z = fmaf(sc[nf][r], CSC, mb4[r]);
                sc[nf][r] = z;
                tm = fmaxf(tm, z);
            }
        }
        tm = fmaxf(tm, __shfl_xor(tm, 16, 64));
        tm = fmaxf(tm, __shfl_xor(tm, 32, 64));
        if (__any(tm > m2 + 11.5f)) {          // rarely taken after tile 0
            const float mn = fmaxf(fmaxf(tm, m2), -60.f);
            const float fac = __builtin_amdgcn_exp2f(m2 - mn);
            m2 = mn;
            lrun *= fac;
            #pragma unroll
            for (int nf = 0; nf < 4; ++nf)
                #pragma unroll
                for (int r = 0; r < 4; ++r)
                    ctx[nf][r] *= fac;
        }

        // ---- P = exp2(z - m2); psum; pack to LDS ----
        float psum = 0.f;
        #pragma unroll
        for (int nf = 0; nf < 4; ++nf) {
            union { bh h4[4]; uint64_t u; } pk;
            #pragma unroll
            for (int r = 0; r < 4; ++r) {
                const float p = __builtin_amdgcn_exp2f(sc[nf][r] - m2);
                psum += p;
                pk.h4[r] = (bh)p;
            }
            *(uint64_t*)((char*)&Plds[w][0][0] + l15 * 128 +
                         ((nf * 32 + l4 * 8) ^ ((l15 & 7) << 4))) = pk.u;
        }
        psum += __shfl_xor(psum, 16, 64);
        psum += __shfl_xor(psum, 32, 64);
        lrun += psum;

        // ---- PV (swapped): ctx[nf] = mfma(V_frag, P_frag) -> D[dk][q=l15] ----
        const char* Vb = (const char*)&Vs[buf][0];
        #pragma unroll
        for (int ks = 0; ks < 2; ++ks) {
            bf16x8 vf[4];
            #pragma unroll
            for (int nf = 0; nf < 4; ++nf) {
                const int row = nf * 16 + l15;
                vf[nf] = *(const bf16x8*)(Vb + row * 128 +
                          ((ks * 64 + l4 * 16) ^ ((row & 7) << 4)));
            }
            const bf16x8 pa = *(const bf16x8*)((const char*)&Plds[w][0][0] + l15 * 128 +
                          ((ks * 64 + l4 * 16) ^ ((l15 & 7) << 4)));
            __builtin_amdgcn_s_setprio(1);
            #pragma unroll
            for (int nf = 0; nf < 4; ++nf)
                ctx[nf] = __builtin_amdgcn_mfma_f32_16x16x32_bf16(
                    vf[nf], pa, ctx[nf], 0, 0, 0);
            __builtin_amdgcn_s_setprio(0);
        }

        WAITLGKM0;
        __builtin_amdgcn_s_barrier();          // all waves done reading Ks/Vs[buf]
        if (t + 2 < NT) stage(buf, kt + 2 * KVB);
    }

    // ---- epilogue: q = l15, dk = nf*16 + l4*4 + r  (8B packed stores) ----
    const float linv = 1.0f / lrun;
    #pragma unroll
    for (int nf = 0; nf < 4; ++nf) {
        union { bh h4[4]; uint64_t u; } pk;
        #pragma unroll
        for (int r = 0; r < 4; ++r)
            pk.h4[r] = (bh)(ctx[nf][r] * linv);
        *(uint64_t*)(O + (size_t)(b * SS + q0 + l15) * DD +
                     h * 64 + nf * 16 + l4 * 4) = pk.u;
    }
}

// ---------------- host launch ----------------
extern "C" void kernel_launch(void* const* d_in, const int* in_sizes, int n_in,
                              void* d_out, int out_size, void* d_ws, size_t ws_size,
                              hipStream_t stream) {
    const int*   seq  = (const int*)  d_in[0];
    const float* mask = (const float*)d_in[1];
    const float* pos  = (const float*)d_in[2];
    const float* emb  = (const float*)d_in[3];
    const float* wq = (const float*)d_in[4];  const float* bq = (const float*)d_in[5];
    const float* wk = (const float*)d_in[6];  const float* bk = (const float*)d_in[7];
    const float* wv = (const float*)d_in[8];  const float* bv = (const float*)d_in[9];
    const float* wo = (const float*)d_in[10]; const float* bo = (const float*)d_in[11];
    const float* ag = (const float*)d_in[12]; const float* ab = (const float*)d_in[13];
    const float* am = (const float*)d_in[14]; const float* av = (const float*)d_in[15];
    const float* d1w = (const float*)d_in[16]; const float* d1b = (const float*)d_in[17];
    const float* d2w = (const float*)d_in[18]; const float* d2b = (const float*)d_in[19];
    const float* fg = (const float*)d_in[20]; const float* fb = (const float*)d_in[21];
    const float* fm = (const float*)d_in[22]; const float* fv = (const float*)d_in[23];

    float* X = (float*)d_out;

    char* p = (char*)d_ws;
    auto take = [&](size_t n) { char* q = p; p += (n + 255) & ~(size_t)255; return q; };
    const size_t WE = (size_t)LL * DD * DD;
    bh* wqt = (bh*)take(WE * 2); bh* wkt = (bh*)take(WE * 2);
    bh* wvt = (bh*)take(WE * 2); bh* wot = (bh*)take(WE * 2);
    bh* w1t = (bh*)take(WE * 2); bh* w2t = (bh*)take(WE * 2);
    const size_t AE = (size_t)NTOK * DD;
    bh* xb   = (bh*)take(AE * 2);
    bh* qb   = (bh*)take(AE * 2);
    bh* kb   = (bh*)take(AE * 2);
    bh* ctxb = (bh*)take(AE * 2);
    bh* subb = (bh*)take(AE * 2);
    bh* h1b  = (bh*)take(AE * 2);
    bh* vT   = (bh*)take(AE * 2);
    bh* vtmp = h1b;   // reuse: v (pre-transpose) is dead before FFN1 writes h1b

    const dim3 wg(16, 16, LL), wb(32, 8);
    wprep<<<wg, wb, 0, stream>>>(wq,  wqt);
    wprep<<<wg, wb, 0, stream>>>(wk,  wkt);
    wprep<<<wg, wb, 0, stream>>>(wv,  wvt);
    wprep<<<wg, wb, 0, stream>>>(wo,  wot);
    wprep<<<wg, wb, 0, stream>>>(d1w, w1t);
    wprep<<<wg, wb, 0, stream>>>(d2w, w2t);

    embed_k<<<dim3(NTOK), dim3(128), 0, stream>>>(seq, emb, pos, X, xb);

    for (int l = 0; l < LL; ++l) {
        const size_t wof = (size_t)l * DD * DD;
        const int    bof = l * DD;
        gemm_bt<0><<<dim3(512), dim3(256), 0, stream>>>(
            xb, wqt + wof, bq + bof, qb, nullptr, nullptr, nullptr, nullptr, nullptr);
        gemm_bt<0><<<dim3(512), dim3(256), 0, stream>>>(
            xb, wkt + wof, bk + bof, kb, nullptr, nullptr, nullptr, nullptr, nullptr);
        gemm_bt<0><<<dim3(512), dim3(256), 0, stream>>>(
            xb, wvt + wof, bv + bof, vtmp, nullptr, nullptr, nullptr, nullptr, nullptr);
        vtrans<<<dim3(SS / 64, HH, BB), dim3(64, 4), 0, stream>>>(vtmp, vT);
        flash_attn<<<dim3(512), dim3(512), 0, stream>>>(qb, kb, vT, mask, ctxb);
        gemm_bt<1><<<dim3(512), dim3(256), 0, stream>>>(
            ctxb, wot + wof, bo + bof, subb, X, ag + bof, ab + bof, am + bof, av + bof);
        gemm_bt<2><<<dim3(512), dim3(256), 0, stream>>>(
            subb, w1t + wof, d1b + bof, h1b, nullptr, nullptr, nullptr, nullptr, nullptr);
        gemm_bt<1><<<dim3(512), dim3(256), 0, stream>>>(
            h1b, w2t + wof, d2b + bof, xb, X, fg + bof, fb + bof, fm + bof, fv + bof);
    }
}

// Round 4
// 480.577 us; speedup vs baseline: 2.7642x; 1.1877x over previous
//
#include <hip/hip_runtime.h>
#include <stdint.h>
#include <stddef.h>

// ---------------- problem constants ----------------
constexpr int BB = 4, SS = 2048, DD = 512, HH = 8, LL = 4;
constexpr int NTOK = BB * SS;          // 8192 tokens
constexpr float BN_EPS = 1e-3f;

using bh = __bf16;
typedef __bf16 bf16x8 __attribute__((ext_vector_type(8)));
typedef float  f32x4  __attribute__((ext_vector_type(4)));

#define DEV __device__ __forceinline__
#define WAITVM(n) asm volatile("s_waitcnt vmcnt(" #n ")" ::: "memory")
#define WAITLGKM0 asm volatile("s_waitcnt lgkmcnt(0)" ::: "memory")

DEV void gload_lds16(const void* g, void* l) {
    __builtin_amdgcn_global_load_lds(
        (const __attribute__((address_space(1))) void*)g,
        (__attribute__((address_space(3))) void*)l, 16, 0, 0);
}

// ---------------- weight prep: f32 [L][512][512] -> bf16 transposed, layer stride ostride ----
__global__ void wprep(const float* __restrict__ in, bh* __restrict__ out, int ostride) {
    __shared__ float t[32][33];
    const float* ip = in + (size_t)blockIdx.z * DD * DD;
    bh* op = out + (size_t)blockIdx.z * ostride;
    const int r0 = blockIdx.y * 32, c0 = blockIdx.x * 32;
    const int tx = threadIdx.x, ty = threadIdx.y;   // 32 x 8
    #pragma unroll
    for (int i = ty; i < 32; i += 8) t[i][tx] = ip[(size_t)(r0 + i) * DD + c0 + tx];
    __syncthreads();
    #pragma unroll
    for (int i = ty; i < 32; i += 8) op[(size_t)(c0 + i) * DD + r0 + tx] = (bh)t[tx][i];
}

// ---------------- mask bias: [B,S] f32 -> 0 / -1e30 ----------------
__global__ void maskprep(const float* __restrict__ mask, float* __restrict__ mb) {
    const int i = ((int)blockIdx.x * 256 + threadIdx.x) * 4;
    const float4 m4 = *(const float4*)(mask + i);
    float4 o;
    o.x = (m4.x == 0.f) ? -1e30f : 0.f;
    o.y = (m4.y == 0.f) ? -1e30f : 0.f;
    o.z = (m4.z == 0.f) ? -1e30f : 0.f;
    o.w = (m4.w == 0.f) ? -1e30f : 0.f;
    *(float4*)(mb + i) = o;
}

// ---------------- embedding + positional -> bf16 ----------------
__global__ void embed_k(const int* __restrict__ seq, const float* __restrict__ emb,
                        const float* __restrict__ pos, bh* __restrict__ xb) {
    const int m = blockIdx.x;                // 0..8191
    const int s = m & (SS - 1);
    const int tok = seq[m];
    const int d = threadIdx.x * 4;           // 128 threads * 4 floats
    const float4 e  = *(const float4*)(emb + (size_t)tok * DD + d);
    const float4 pz = *(const float4*)(pos + (size_t)s * DD + d);
    union { bh h[4]; uint64_t u; } pk;
    pk.h[0] = (bh)(e.x + pz.x); pk.h[1] = (bh)(e.y + pz.y);
    pk.h[2] = (bh)(e.z + pz.z); pk.h[3] = (bh)(e.w + pz.w);
    *(uint64_t*)(xb + (size_t)m * DD + d) = pk.u;
}

// ---------------- GEMM core macros shared by gemm_bt / gemm_qkv ----------------
// A[M,512] @ Bt[N,512]^T, BM=128, BN=64, BK=64, double-buffered, counted vmcnt.

// ---------------- generic GEMM with epilogues ----------------
// EP 1: t = resb + acc + bias; s = BN(t); outb = bf16(s); if WF32: Xo = s
// EP 2: outb = bf16(relu(acc + bias))
template <int EP, bool WF32>
__global__ __launch_bounds__(256, 2)
void gemm_bt(const bh* __restrict__ A, const bh* __restrict__ Bt,
             const float* __restrict__ bias, bh* __restrict__ outb,
             const bh* __restrict__ resb, float* __restrict__ Xo,
             const float* __restrict__ gamma, const float* __restrict__ beta,
             const float* __restrict__ mean, const float* __restrict__ var) {
    constexpr int BM = 128, BN = 64, BK = 64, NKT = DD / BK;
    __shared__ __align__(16) bh As[2][BM * BK];
    __shared__ __align__(16) bh Bs[2][BN * BK];

    const int tid = threadIdx.x;
    const int w = tid >> 6, lane = tid & 63;
    const int l15 = lane & 15, l4 = lane >> 4;
    const int i = (int)blockIdx.x;
    const int xcd = i & 7, j = i >> 3;        // j 0..63
    const int bm = xcd * 8 + (j >> 3);
    const int bn = j & 7;
    const int m0 = bm * BM, n0 = bn * BN;
    const int wr = w >> 1, wc = w & 1;

    f32x4 acc[4][2] = {};
    const int sr = lane >> 3;
    const int cbx = (lane & 7) ^ sr;

    auto stage = [&](int buf, int kk) {
        #pragma unroll
        for (int ii = 0; ii < 4; ++ii) {
            const int idx = w * 4 + ii;
            const int r = idx * 8 + sr;
            gload_lds16(A + (size_t)(m0 + r) * DD + kk + 8 * cbx, &As[buf][idx * 512]);
        }
        #pragma unroll
        for (int ii = 0; ii < 2; ++ii) {
            const int idx = w * 2 + ii;
            const int r = idx * 8 + sr;
            gload_lds16(Bt + (size_t)(n0 + r) * DD + kk + 8 * cbx, &Bs[buf][idx * 512]);
        }
    };

    stage(0, 0);
    stage(1, BK);

    for (int kt = 0; kt < NKT; ++kt) {
        const int buf = kt & 1;
        if (kt + 1 < NKT) { WAITVM(6); } else { WAITVM(0); }
        __builtin_amdgcn_s_barrier();

        const char* Ab = (const char*)&As[buf][0];
        const char* Bb = (const char*)&Bs[buf][0];
        #pragma unroll
        for (int ks = 0; ks < 2; ++ks) {
            bf16x8 af[4], bfr[2];
            const int cby = ks * 64 + l4 * 16;
            #pragma unroll
            for (int mf = 0; mf < 4; ++mf) {
                const int row = wr * 64 + mf * 16 + l15;
                af[mf] = *(const bf16x8*)(Ab + row * 128 + (cby ^ ((row & 7) << 4)));
            }
            #pragma unroll
            for (int nf = 0; nf < 2; ++nf) {
                const int row = wc * 32 + nf * 16 + l15;
                bfr[nf] = *(const bf16x8*)(Bb + row * 128 + (cby ^ ((row & 7) << 4)));
            }
            #pragma unroll
            for (int mf = 0; mf < 4; ++mf)
                #pragma unroll
                for (int nf = 0; nf < 2; ++nf)
                    acc[mf][nf] = __builtin_amdgcn_mfma_f32_16x16x32_bf16(
                        af[mf], bfr[nf], acc[mf][nf], 0, 0, 0);
        }
        WAITLGKM0;
        __builtin_amdgcn_s_barrier();
        if (kt + 2 < NKT) stage(buf, (kt + 2) * BK);
    }

    #pragma unroll
    for (int nf = 0; nf < 2; ++nf) {
        const int n = n0 + wc * 32 + nf * 16 + l15;
        const float bi = bias[n];
        float g = 0.f, be = 0.f, mu = 0.f, iv = 0.f;
        if constexpr (EP == 1) {
            g = gamma[n]; be = beta[n]; mu = mean[n];
            iv = rsqrtf(var[n] + BN_EPS);
        }
        #pragma unroll
        for (int mf = 0; mf < 4; ++mf) {
            #pragma unroll
            for (int r = 0; r < 4; ++r) {
                const int m = m0 + wr * 64 + mf * 16 + l4 * 4 + r;
                const size_t off = (size_t)m * DD + n;
                const float v = acc[mf][nf][r] + bi;
                if constexpr (EP == 2) {
                    outb[off] = (bh)fmaxf(v, 0.f);
                } else {
                    const float t = (float)resb[off] + v;
                    const float s = (t - mu) * iv * g + be;
                    outb[off] = (bh)s;
                    if constexpr (WF32) Xo[off] = s;
                }
            }
        }
    }
}

// ---------------- fused QKV GEMM: C[8192,1536] = xb @ Wcat^T; V written transposed ---------
__global__ __launch_bounds__(256, 3)
void gemm_qkv(const bh* __restrict__ A, const bh* __restrict__ Bt,
              const float* __restrict__ bq, const float* __restrict__ bk,
              const float* __restrict__ bv,
              bh* __restrict__ qb, bh* __restrict__ kb, bh* __restrict__ vT) {
    constexpr int BM = 128, BN = 64, BK = 64, NKT = DD / BK;
    __shared__ __align__(16) bh As[2][BM * BK];
    __shared__ __align__(16) bh Bs[2][BN * BK];

    const int tid = threadIdx.x;
    const int w = tid >> 6, lane = tid & 63;
    const int l15 = lane & 15, l4 = lane >> 4;
    const int i = (int)blockIdx.x;
    const int xcd = i & 7, j = i >> 3;        // j 0..191
    const int bm = xcd * 8 + (j & 7);         // 0..63
    const int bn = j >> 3;                    // 0..23
    const int m0 = bm * BM, n0 = bn * BN;
    const int wr = w >> 1, wc = w & 1;

    f32x4 acc[4][2] = {};
    const int sr = lane >> 3;
    const int cbx = (lane & 7) ^ sr;

    auto stage = [&](int buf, int kk) {
        #pragma unroll
        for (int ii = 0; ii < 4; ++ii) {
            const int idx = w * 4 + ii;
            const int r = idx * 8 + sr;
            gload_lds16(A + (size_t)(m0 + r) * DD + kk + 8 * cbx, &As[buf][idx * 512]);
        }
        #pragma unroll
        for (int ii = 0; ii < 2; ++ii) {
            const int idx = w * 2 + ii;
            const int r = idx * 8 + sr;
            gload_lds16(Bt + (size_t)(n0 + r) * DD + kk + 8 * cbx, &Bs[buf][idx * 512]);
        }
    };

    stage(0, 0);
    stage(1, BK);

    for (int kt = 0; kt < NKT; ++kt) {
        const int buf = kt & 1;
        if (kt + 1 < NKT) { WAITVM(6); } else { WAITVM(0); }
        __builtin_amdgcn_s_barrier();

        const char* Ab = (const char*)&As[buf][0];
        const char* Bb = (const char*)&Bs[buf][0];
        #pragma unroll
        for (int ks = 0; ks < 2; ++ks) {
            bf16x8 af[4], bfr[2];
            const int cby = ks * 64 + l4 * 16;
            #pragma unroll
            for (int mf = 0; mf < 4; ++mf) {
                const int row = wr * 64 + mf * 16 + l15;
                af[mf] = *(const bf16x8*)(Ab + row * 128 + (cby ^ ((row & 7) << 4)));
            }
            #pragma unroll
            for (int nf = 0; nf < 2; ++nf) {
                const int row = wc * 32 + nf * 16 + l15;
                bfr[nf] = *(const bf16x8*)(Bb + row * 128 + (cby ^ ((row & 7) << 4)));
            }
            #pragma unroll
            for (int mf = 0; mf < 4; ++mf)
                #pragma unroll
                for (int nf = 0; nf < 2; ++nf)
                    acc[mf][nf] = __builtin_amdgcn_mfma_f32_16x16x32_bf16(
                        af[mf], bfr[nf], acc[mf][nf], 0, 0, 0);
        }
        WAITLGKM0;
        __builtin_amdgcn_s_barrier();
        if (kt + 2 < NKT) stage(buf, (kt + 2) * BK);
    }

    const int part = n0 >> 9;                 // uniform per block: 0=Q 1=K 2=V
    #pragma unroll
    for (int nf = 0; nf < 2; ++nf) {
        const int n = n0 + wc * 32 + nf * 16 + l15;
        const int nn = n & 511;
        const float bi = (part == 0 ? bq : part == 1 ? bk : bv)[nn];
        if (part < 2) {
            bh* out = part ? kb : qb;
            #pragma unroll
            for (int mf = 0; mf < 4; ++mf)
                #pragma unroll
                for (int r = 0; r < 4; ++r) {
                    const int m = m0 + wr * 64 + mf * 16 + l4 * 4 + r;
                    out[(size_t)m * DD + nn] = (bh)(acc[mf][nf][r] + bi);
                }
        } else {
            const int hh = nn >> 6, dk = nn & 63;
            #pragma unroll
            for (int mf = 0; mf < 4; ++mf) {
                const int m = m0 + wr * 64 + mf * 16 + l4 * 4;   // r = 0..3 consecutive
                const int bb2 = m >> 11, s = m & (SS - 1);
                union { bh h4[4]; uint64_t u; } pk;
                #pragma unroll
                for (int r = 0; r < 4; ++r)
                    pk.h4[r] = (bh)(acc[mf][nf][r] + bi);
                *(uint64_t*)(vT + ((size_t)((bb2 * HH + hh) * 64) + dk) * SS + s) = pk.u;
            }
        }
    }
}

// ---------------- flash attention v4 ----------------
// grid 1024 (XCD-pinned), 2 waves x 32q = 64 q/block, KVB=64. 4 blocks/CU (LDS 40KB).
// Swapped MFMA; in-reg softmax (log2 domain, defer-max); lrun via ones-MFMA column;
// mask bias from precomputed global f32 (issued M-before-S so its wait is vmcnt(8)).
__global__ __launch_bounds__(128, 2)
void flash_attn(const bh* __restrict__ Q, const bh* __restrict__ K,
                const bh* __restrict__ VT, const float* __restrict__ mb,
                bh* __restrict__ O) {
    constexpr int KVB = 64, NT = SS / KVB;     // 32 tiles
    constexpr float CSC = 0.18033688f;         // 0.125 * log2(e)
    __shared__ __align__(16) bh Ks[2][KVB * 64];   // 16 KB
    __shared__ __align__(16) bh Vs[2][64 * KVB];   // 16 KB
    __shared__ __align__(16) bh Plds[2][2][16 * 64]; // 8 KB wave/set-private

    const int tid = threadIdx.x;
    const int w = tid >> 6, lane = tid & 63;
    const int l15 = lane & 15, l4 = lane >> 4;

    const int i = (int)blockIdx.x;
    const int xcd = i & 7, j = i >> 3;         // j 0..127
    const int g = xcd * 4 + (j >> 5);          // (b,h) group 0..31
    const int qt = j & 31;
    const int h = g & 7, b = g >> 3;

    const int q0 = qt * 64 + w * 32;

    bf16x8 qf[2][2];
    #pragma unroll
    for (int st = 0; st < 2; ++st) {
        const bh* qp = Q + (size_t)(b * SS + q0 + st * 16 + l15) * DD + h * 64 + l4 * 8;
        qf[st][0] = *(const bf16x8*)qp;
        qf[st][1] = *(const bf16x8*)(qp + 32);
    }

    f32x4 ctx[2][4] = {};
    f32x4 accl[2] = {};
    float m2[2] = {-3e38f, -3e38f};

    bf16x8 ones;
    #pragma unroll
    for (int z = 0; z < 8; ++z) ones[z] = (bh)1.0f;

    const int sr = lane >> 3;
    const int cbx = (lane & 7) ^ sr;
    const bh* kg = K + (size_t)b * SS * DD + h * 64 + 8 * cbx;
    const bh* vg = VT + (size_t)((b * HH + h) * 64) * SS + 8 * cbx;
    const float* mbb = mb + (size_t)b * SS;

    auto stage = [&](int buf, int kt) {
        #pragma unroll
        for (int ii = 0; ii < 4; ++ii) {
            const int idx = w * 4 + ii;
            const int r = idx * 8 + sr;
            gload_lds16(kg + (size_t)(kt + r) * DD, &Ks[buf][idx * 512]);
        }
        #pragma unroll
        for (int ii = 0; ii < 4; ++ii) {
            const int idx = w * 4 + ii;
            const int r = idx * 8 + sr;
            gload_lds16(vg + (size_t)r * SS + kt, &Vs[buf][idx * 512]);
        }
    };

    f32x4 mbc[4];
    stage(0, 0);
    stage(1, KVB);
    #pragma unroll
    for (int nf = 0; nf < 4; ++nf)
        mbc[nf] = *(const f32x4*)(mbb + nf * 16 + l4 * 4);
    __syncthreads();

    for (int t = 0; t < NT; ++t) {
        const int buf = t & 1;
        const int kt = t * KVB;
        if (t > 0) {
            if (t + 1 < NT) { WAITVM(12); } else { WAITVM(4); }
            __builtin_amdgcn_s_barrier();
        }

        // ---- QK^T (swapped): D[key][q=l15] ----
        f32x4 sc[2][4] = {};
        const char* Kb = (const char*)&Ks[buf][0];
        #pragma unroll
        for (int ks = 0; ks < 2; ++ks) {
            bf16x8 kf[4];
            #pragma unroll
            for (int nf = 0; nf < 4; ++nf) {
                const int row = nf * 16 + l15;
                kf[nf] = *(const bf16x8*)(Kb + row * 128 +
                          ((ks * 64 + l4 * 16) ^ ((row & 7) << 4)));
            }
            __builtin_amdgcn_s_setprio(1);
            #pragma unroll
            for (int st = 0; st < 2; ++st)
                #pragma unroll
                for (int nf = 0; nf < 4; ++nf)
                    sc[st][nf] = __builtin_amdgcn_mfma_f32_16x16x32_bf16(
                        kf[nf], qf[st][ks], sc[st][nf], 0, 0, 0);
            __builtin_amdgcn_s_setprio(0);
        }

        // ---- softmax (log2 domain, defer-max), per q-set ----
        #pragma unroll
        for (int st = 0; st < 2; ++st) {
            #pragma unroll
            for (int nf = 0; nf < 4; ++nf)
                #pragma unroll
                for (int r = 0; r < 4; ++r)
                    sc[st][nf][r] = fmaf(sc[st][nf][r], CSC, mbc[nf][r]);
            float tm;
            {
                f32x4 m01, m23;
                #pragma unroll
                for (int r = 0; r < 4; ++r) {
                    m01[r] = fmaxf(sc[st][0][r], sc[st][1][r]);
                    m23[r] = fmaxf(sc[st][2][r], sc[st][3][r]);
                }
                const float a = fmaxf(fmaxf(m01[0], m01[1]), fmaxf(m01[2], m01[3]));
                const float c = fmaxf(fmaxf(m23[0], m23[1]), fmaxf(m23[2], m23[3]));
                tm = fmaxf(a, c);
            }
            tm = fmaxf(tm, __shfl_xor(tm, 16, 64));
            tm = fmaxf(tm, __shfl_xor(tm, 32, 64));
            if (__any(tm > m2[st] + 11.5f)) {
                const float mn = fmaxf(fmaxf(tm, m2[st]), -60.f);
                const float fac = __builtin_amdgcn_exp2f(m2[st] - mn);
                m2[st] = mn;
                accl[st] *= fac;
                #pragma unroll
                for (int nf = 0; nf < 4; ++nf)
                    #pragma unroll
                    for (int r = 0; r < 4; ++r)
                        ctx[st][nf][r] *= fac;
            }
            #pragma unroll
            for (int nf = 0; nf < 4; ++nf) {
                union { bh h4[4]; uint64_t u; } pk;
                #pragma unroll
                for (int r = 0; r < 4; ++r)
                    pk.h4[r] = (bh)__builtin_amdgcn_exp2f(sc[st][nf][r] - m2[st]);
                *(uint64_t*)((char*)&Plds[w][st][0] + l15 * 128 +
                             ((nf * 32 + l4 * 8) ^ ((l15 & 7) << 4))) = pk.u;
            }
        }

        // ---- PV (swapped): D[dk][q=l15]; lrun via ones-fragment MFMA ----
        const char* Vb = (const char*)&Vs[buf][0];
        #pragma unroll
        for (int ks = 0; ks < 2; ++ks) {
            bf16x8 vf[4];
            #pragma unroll
            for (int nf = 0; nf < 4; ++nf) {
                const int row = nf * 16 + l15;
                vf[nf] = *(const bf16x8*)(Vb + row * 128 +
                          ((ks * 64 + l4 * 16) ^ ((row & 7) << 4)));
            }
            bf16x8 pa[2];
            #pragma unroll
            for (int st = 0; st < 2; ++st)
                pa[st] = *(const bf16x8*)((const char*)&Plds[w][st][0] + l15 * 128 +
                          ((ks * 64 + l4 * 16) ^ ((l15 & 7) << 4)));
            __builtin_amdgcn_s_setprio(1);
            #pragma unroll
            for (int st = 0; st < 2; ++st) {
                #pragma unroll
                for (int nf = 0; nf < 4; ++nf)
                    ctx[st][nf] = __builtin_amdgcn_mfma_f32_16x16x32_bf16(
                        vf[nf], pa[st], ctx[st][nf], 0, 0, 0);
                accl[st] = __builtin_amdgcn_mfma_f32_16x16x32_bf16(
                    ones, pa[st], accl[st], 0, 0, 0);
            }
            __builtin_amdgcn_s_setprio(0);
        }

        WAITLGKM0;
        __builtin_amdgcn_s_barrier();
        if (t + 1 < NT) {       // mask bias for t+1: issued BEFORE stage(t+2)
            #pragma unroll
            for (int nf = 0; nf < 4; ++nf)
                mbc[nf] = *(const f32x4*)(mbb + kt + KVB + nf * 16 + l4 * 4);
        }
        if (t + 2 < NT) stage(buf, kt + 2 * KVB);
    }

    // ---- epilogue: q = l15, dk = nf*16 + l4*4 + r ----
    #pragma unroll
    for (int st = 0; st < 2; ++st) {
        const float linv = 1.0f / accl[st][0];
        #pragma unroll
        for (int nf = 0; nf < 4; ++nf) {
            union { bh h4[4]; uint64_t u; } pk;
            #pragma unroll
            for (int r = 0; r < 4; ++r)
                pk.h4[r] = (bh)(ctx[st][nf][r] * linv);
            *(uint64_t*)(O + (size_t)(b * SS + q0 + st * 16 + l15) * DD +
                         h * 64 + nf * 16 + l4 * 4) = pk.u;
        }
    }
}

// ---------------- host launch ----------------
extern "C" void kernel_launch(void* const* d_in, const int* in_sizes, int n_in,
                              void* d_out, int out_size, void* d_ws, size_t ws_size,
                              hipStream_t stream) {
    const int*   seq  = (const int*)  d_in[0];
    const float* mask = (const float*)d_in[1];
    const float* pos  = (const float*)d_in[2];
    const float* emb  = (const float*)d_in[3];
    const float* wq = (const float*)d_in[4];  const float* bq = (const float*)d_in[5];
    const float* wk = (const float*)d_in[6];  const float* bk = (const float*)d_in[7];
    const float* wv = (const float*)d_in[8];  const float* bv = (const float*)d_in[9];
    const float* wo = (const float*)d_in[10]; const float* bo = (const float*)d_in[11];
    const float* ag = (const float*)d_in[12]; const float* ab = (const float*)d_in[13];
    const float* am = (const float*)d_in[14]; const float* av = (const float*)d_in[15];
    const float* d1w = (const float*)d_in[16]; const float* d1b = (const float*)d_in[17];
    const float* d2w = (const float*)d_in[18]; const float* d2b = (const float*)d_in[19];
    const float* fg = (const float*)d_in[20]; const float* fb = (const float*)d_in[21];
    const float* fm = (const float*)d_in[22]; const float* fv = (const float*)d_in[23];

    float* X = (float*)d_out;

    char* p = (char*)d_ws;
    auto take = [&](size_t n) { char* q = p; p += (n + 255) & ~(size_t)255; return q; };
    const size_t WE  = (size_t)LL * DD * DD;          // per-matrix weight elems
    const size_t WQE = (size_t)LL * 3 * DD * DD;      // fused QKV elems
    bh* wcat = (bh*)take(WQE * 2);
    bh* wot = (bh*)take(WE * 2);
    bh* w1t = (bh*)take(WE * 2);
    bh* w2t = (bh*)take(WE * 2);
    const size_t AE = (size_t)NTOK * DD;
    bh* xb   = (bh*)take(AE * 2);
    bh* qb   = (bh*)take(AE * 2);
    bh* kb   = (bh*)take(AE * 2);
    bh* ctxb = (bh*)take(AE * 2);
    bh* subb = (bh*)take(AE * 2);
    bh* h1b  = (bh*)take(AE * 2);
    bh* vT   = (bh*)take(AE * 2);
    float* mbias = (float*)take((size_t)BB * SS * 4);

    const int QKV_OS = 3 * DD * DD;                   // 1536*512 per layer
    const dim3 wg(16, 16, LL), wb(32, 8);
    wprep<<<wg, wb, 0, stream>>>(wq,  wcat + 0 * DD * DD, QKV_OS);
    wprep<<<wg, wb, 0, stream>>>(wk,  wcat + 1 * DD * DD, QKV_OS);
    wprep<<<wg, wb, 0, stream>>>(wv,  wcat + 2 * DD * DD, QKV_OS);
    wprep<<<wg, wb, 0, stream>>>(wo,  wot, DD * DD);
    wprep<<<wg, wb, 0, stream>>>(d1w, w1t, DD * DD);
    wprep<<<wg, wb, 0, stream>>>(d2w, w2t, DD * DD);

    maskprep<<<dim3(BB * SS / 1024), dim3(256), 0, stream>>>(mask, mbias);
    embed_k<<<dim3(NTOK), dim3(128), 0, stream>>>(seq, emb, pos, xb);

    for (int l = 0; l < LL; ++l) {
        const size_t wof = (size_t)l * DD * DD;
        const int    bof = l * DD;
        gemm_qkv<<<dim3(1536), dim3(256), 0, stream>>>(
            xb, wcat + (size_t)l * QKV_OS, bq + bof, bk + bof, bv + bof, qb, kb, vT);
        flash_attn<<<dim3(1024), dim3(128), 0, stream>>>(qb, kb, vT, mbias, ctxb);
        gemm_bt<1, false><<<dim3(512), dim3(256), 0, stream>>>(
            ctxb, wot + wof, bo + bof, subb, xb, nullptr,
            ag + bof, ab + bof, am + bof, av + bof);
        gemm_bt<2, false><<<dim3(512), dim3(256), 0, stream>>>(
            subb, w1t + wof, d1b + bof, h1b, nullptr, nullptr,
            nullptr, nullptr, nullptr, nullptr);
        if (l + 1 < LL) {
            gemm_bt<1, false><<<dim3(512), dim3(256), 0, stream>>>(
                h1b, w2t + wof, d2b + bof, xb, subb, nullptr,
                fg + bof, fb + bof, fm + bof, fv + bof);
        } else {
            gemm_bt<1, true><<<dim3(512), dim3(256), 0, stream>>>(
                h1b, w2t + wof, d2b + bof, xb, subb, X,
                fg + bof, fb + bof, fm + bof, fv + bof);
        }
    }
}

// Round 5
// 467.860 us; speedup vs baseline: 2.8393x; 1.0272x over previous
//
#include <hip/hip_runtime.h>
#include <stdint.h>
#include <stddef.h>

// ---------------- problem constants ----------------
constexpr int BB = 4, SS = 2048, DD = 512, HH = 8, LL = 4;
constexpr int NTOK = BB * SS;          // 8192 tokens
constexpr float BN_EPS = 1e-3f;

using bh = __bf16;
typedef __bf16 bf16x8 __attribute__((ext_vector_type(8)));
typedef float  f32x4  __attribute__((ext_vector_type(4)));

#define DEV __device__ __forceinline__
#define WAITVM(n) asm volatile("s_waitcnt vmcnt(" #n ")" ::: "memory")
#define WAITLGKM0 asm volatile("s_waitcnt lgkmcnt(0)" ::: "memory")

DEV void gload_lds16(const void* g, void* l) {
    __builtin_amdgcn_global_load_lds(
        (const __attribute__((address_space(1))) void*)g,
        (__attribute__((address_space(3))) void*)l, 16, 0, 0);
}

// ---------------- weight prep: f32 [L][512][512] -> bf16 transposed, layer stride ostride ----
__global__ void wprep(const float* __restrict__ in, bh* __restrict__ out, int ostride) {
    __shared__ float t[32][33];
    const float* ip = in + (size_t)blockIdx.z * DD * DD;
    bh* op = out + (size_t)blockIdx.z * ostride;
    const int r0 = blockIdx.y * 32, c0 = blockIdx.x * 32;
    const int tx = threadIdx.x, ty = threadIdx.y;   // 32 x 8
    #pragma unroll
    for (int i = ty; i < 32; i += 8) t[i][tx] = ip[(size_t)(r0 + i) * DD + c0 + tx];
    __syncthreads();
    #pragma unroll
    for (int i = ty; i < 32; i += 8) op[(size_t)(c0 + i) * DD + r0 + tx] = (bh)t[tx][i];
}

// ---------------- mask bias: [B,S] f32 -> 0 / -1e30 ----------------
__global__ void maskprep(const float* __restrict__ mask, float* __restrict__ mb) {
    const int i = ((int)blockIdx.x * 256 + threadIdx.x) * 4;
    const float4 m4 = *(const float4*)(mask + i);
    float4 o;
    o.x = (m4.x == 0.f) ? -1e30f : 0.f;
    o.y = (m4.y == 0.f) ? -1e30f : 0.f;
    o.z = (m4.z == 0.f) ? -1e30f : 0.f;
    o.w = (m4.w == 0.f) ? -1e30f : 0.f;
    *(float4*)(mb + i) = o;
}

// ---------------- embedding + positional -> bf16 ----------------
__global__ void embed_k(const int* __restrict__ seq, const float* __restrict__ emb,
                        const float* __restrict__ pos, bh* __restrict__ xb) {
    const int m = blockIdx.x;                // 0..8191
    const int s = m & (SS - 1);
    const int tok = seq[m];
    const int d = threadIdx.x * 4;           // 128 threads * 4 floats
    const float4 e  = *(const float4*)(emb + (size_t)tok * DD + d);
    const float4 pz = *(const float4*)(pos + (size_t)s * DD + d);
    union { bh h[4]; uint64_t u; } pk;
    pk.h[0] = (bh)(e.x + pz.x); pk.h[1] = (bh)(e.y + pz.y);
    pk.h[2] = (bh)(e.z + pz.z); pk.h[3] = (bh)(e.w + pz.w);
    *(uint64_t*)(xb + (size_t)m * DD + d) = pk.u;
}

// ---------------- GEMM 64x64 tile, one barrier per k-tile, grid 1024 ----------------
// EP 1: t = resb + acc + bias; s = BN(t); outb = bf16(s); if WF32: Xo = s
// EP 2: outb = bf16(relu(acc + bias))
template <int EP, bool WF32>
__global__ __launch_bounds__(256, 4)
void gemm64(const bh* __restrict__ A, const bh* __restrict__ Bt,
            const float* __restrict__ bias, bh* __restrict__ outb,
            const bh* __restrict__ resb, float* __restrict__ Xo,
            const float* __restrict__ gamma, const float* __restrict__ beta,
            const float* __restrict__ mean, const float* __restrict__ var) {
    constexpr int BK = 64, NKT = DD / BK;        // 8 k-tiles
    __shared__ __align__(16) bh As[2][64 * BK];  // 2 x 8 KB
    __shared__ __align__(16) bh Bs[2][64 * BK];  // 2 x 8 KB

    const int tid = threadIdx.x;
    const int w = tid >> 6, lane = tid & 63;
    const int l15 = lane & 15, l4 = lane >> 4;
    const int i = (int)blockIdx.x;
    const int xcd = i & 7, j = i >> 3;           // j 0..127
    const int bm = xcd * 16 + (j >> 3);          // 0..127
    const int bn = j & 7;                        // 0..7
    const int m0 = bm * 64, n0 = bn * 64;
    const int wr = w >> 1, wc = w & 1;           // wave tile 32x32

    f32x4 acc[2][2] = {};
    const int sr = lane >> 3;
    const int cbx = (lane & 7) ^ sr;

    auto stage = [&](int buf, int kk) {
        #pragma unroll
        for (int ii = 0; ii < 2; ++ii) {
            const int idx = w * 2 + ii;
            const int r = idx * 8 + sr;
            gload_lds16(A + (size_t)(m0 + r) * DD + kk + 8 * cbx, &As[buf][idx * 512]);
            gload_lds16(Bt + (size_t)(n0 + r) * DD + kk + 8 * cbx, &Bs[buf][idx * 512]);
        }
    };

    stage(0, 0);
    __syncthreads();

    for (int kt = 0; kt < NKT; ++kt) {
        const int buf = kt & 1;
        if (kt > 0) { WAITVM(0); __builtin_amdgcn_s_barrier(); }
        if (kt + 1 < NKT) stage(buf ^ 1, (kt + 1) * BK);

        const char* Ab = (const char*)&As[buf][0];
        const char* Bb = (const char*)&Bs[buf][0];
        #pragma unroll
        for (int ks = 0; ks < 2; ++ks) {
            bf16x8 af[2], bfr[2];
            const int cby = ks * 64 + l4 * 16;
            #pragma unroll
            for (int mf = 0; mf < 2; ++mf) {
                const int row = wr * 32 + mf * 16 + l15;
                af[mf] = *(const bf16x8*)(Ab + row * 128 + (cby ^ ((row & 7) << 4)));
            }
            #pragma unroll
            for (int nf = 0; nf < 2; ++nf) {
                const int row = wc * 32 + nf * 16 + l15;
                bfr[nf] = *(const bf16x8*)(Bb + row * 128 + (cby ^ ((row & 7) << 4)));
            }
            __builtin_amdgcn_s_setprio(1);
            #pragma unroll
            for (int mf = 0; mf < 2; ++mf)
                #pragma unroll
                for (int nf = 0; nf < 2; ++nf)
                    acc[mf][nf] = __builtin_amdgcn_mfma_f32_16x16x32_bf16(
                        af[mf], bfr[nf], acc[mf][nf], 0, 0, 0);
            __builtin_amdgcn_s_setprio(0);
        }
    }

    // epilogue: m = l4*4 + r rows, n = l15 cols
    #pragma unroll
    for (int nf = 0; nf < 2; ++nf) {
        const int n = n0 + wc * 32 + nf * 16 + l15;
        const float bi = bias[n];
        float g = 0.f, be = 0.f, mu = 0.f, iv = 0.f;
        if constexpr (EP == 1) {
            g = gamma[n]; be = beta[n]; mu = mean[n];
            iv = rsqrtf(var[n] + BN_EPS);
        }
        #pragma unroll
        for (int mf = 0; mf < 2; ++mf) {
            #pragma unroll
            for (int r = 0; r < 4; ++r) {
                const int m = m0 + wr * 32 + mf * 16 + l4 * 4 + r;
                const size_t off = (size_t)m * DD + n;
                const float v = acc[mf][nf][r] + bi;
                if constexpr (EP == 2) {
                    outb[off] = (bh)fmaxf(v, 0.f);
                } else {
                    const float t = (float)resb[off] + v;
                    const float s = (t - mu) * iv * g + be;
                    outb[off] = (bh)s;
                    if constexpr (WF32) Xo[off] = s;
                }
            }
        }
    }
}

// ---------------- fused QKV GEMM: C[8192,1536] = xb @ Wcat^T; V written transposed ---------
__global__ __launch_bounds__(256, 3)
void gemm_qkv(const bh* __restrict__ A, const bh* __restrict__ Bt,
              const float* __restrict__ bq, const float* __restrict__ bk,
              const float* __restrict__ bv,
              bh* __restrict__ qb, bh* __restrict__ kb, bh* __restrict__ vT) {
    constexpr int BM = 128, BN = 64, BK = 64, NKT = DD / BK;
    __shared__ __align__(16) bh As[2][BM * BK];
    __shared__ __align__(16) bh Bs[2][BN * BK];

    const int tid = threadIdx.x;
    const int w = tid >> 6, lane = tid & 63;
    const int l15 = lane & 15, l4 = lane >> 4;
    const int i = (int)blockIdx.x;
    const int xcd = i & 7, j = i >> 3;        // j 0..191
    const int bm = xcd * 8 + (j & 7);         // 0..63
    const int bn = j >> 3;                    // 0..23
    const int m0 = bm * BM, n0 = bn * BN;
    const int wr = w >> 1, wc = w & 1;

    f32x4 acc[4][2] = {};
    const int sr = lane >> 3;
    const int cbx = (lane & 7) ^ sr;

    auto stage = [&](int buf, int kk) {
        #pragma unroll
        for (int ii = 0; ii < 4; ++ii) {
            const int idx = w * 4 + ii;
            const int r = idx * 8 + sr;
            gload_lds16(A + (size_t)(m0 + r) * DD + kk + 8 * cbx, &As[buf][idx * 512]);
        }
        #pragma unroll
        for (int ii = 0; ii < 2; ++ii) {
            const int idx = w * 2 + ii;
            const int r = idx * 8 + sr;
            gload_lds16(Bt + (size_t)(n0 + r) * DD + kk + 8 * cbx, &Bs[buf][idx * 512]);
        }
    };

    stage(0, 0);
    stage(1, BK);

    for (int kt = 0; kt < NKT; ++kt) {
        const int buf = kt & 1;
        if (kt + 1 < NKT) { WAITVM(6); } else { WAITVM(0); }
        __builtin_amdgcn_s_barrier();

        const char* Ab = (const char*)&As[buf][0];
        const char* Bb = (const char*)&Bs[buf][0];
        #pragma unroll
        for (int ks = 0; ks < 2; ++ks) {
            bf16x8 af[4], bfr[2];
            const int cby = ks * 64 + l4 * 16;
            #pragma unroll
            for (int mf = 0; mf < 4; ++mf) {
                const int row = wr * 64 + mf * 16 + l15;
                af[mf] = *(const bf16x8*)(Ab + row * 128 + (cby ^ ((row & 7) << 4)));
            }
            #pragma unroll
            for (int nf = 0; nf < 2; ++nf) {
                const int row = wc * 32 + nf * 16 + l15;
                bfr[nf] = *(const bf16x8*)(Bb + row * 128 + (cby ^ ((row & 7) << 4)));
            }
            #pragma unroll
            for (int mf = 0; mf < 4; ++mf)
                #pragma unroll
                for (int nf = 0; nf < 2; ++nf)
                    acc[mf][nf] = __builtin_amdgcn_mfma_f32_16x16x32_bf16(
                        af[mf], bfr[nf], acc[mf][nf], 0, 0, 0);
        }
        WAITLGKM0;
        __builtin_amdgcn_s_barrier();
        if (kt + 2 < NKT) stage(buf, (kt + 2) * BK);
    }

    const int part = n0 >> 9;                 // uniform per block: 0=Q 1=K 2=V
    #pragma unroll
    for (int nf = 0; nf < 2; ++nf) {
        const int n = n0 + wc * 32 + nf * 16 + l15;
        const int nn = n & 511;
        const float bi = (part == 0 ? bq : part == 1 ? bk : bv)[nn];
        if (part < 2) {
            bh* out = part ? kb : qb;
            #pragma unroll
            for (int mf = 0; mf < 4; ++mf)
                #pragma unroll
                for (int r = 0; r < 4; ++r) {
                    const int m = m0 + wr * 64 + mf * 16 + l4 * 4 + r;
                    out[(size_t)m * DD + nn] = (bh)(acc[mf][nf][r] + bi);
                }
        } else {
            const int hh = nn >> 6, dk = nn & 63;
            #pragma unroll
            for (int mf = 0; mf < 4; ++mf) {
                const int m = m0 + wr * 64 + mf * 16 + l4 * 4;   // r = 0..3 consecutive
                const int bb2 = m >> 11, s = m & (SS - 1);
                union { bh h4[4]; uint64_t u; } pk;
                #pragma unroll
                for (int r = 0; r < 4; ++r)
                    pk.h4[r] = (bh)(acc[mf][nf][r] + bi);
                *(uint64_t*)(vT + ((size_t)((bb2 * HH + hh) * 64) + dk) * SS + s) = pk.u;
            }
        }
    }
}

// ---------------- flash attention v5 ----------------
// grid 1024 (XCD-pinned), 4 waves x 16q = 64 q/block, KVB=32, LDS 21KB ->
// 4 blocks/CU x 4 waves = 16 waves/CU (50%). One barrier per tile, counted vmcnt.
// Swapped MFMA, in-reg softmax (log2 domain), shfl-free defer-max check,
// lrun via ones-MFMA, K xor-swizzle (row&7), V xor-swizzle (row&3), P stride-80.
__global__ __launch_bounds__(256, 4)
void flash_attn(const bh* __restrict__ Q, const bh* __restrict__ K,
                const bh* __restrict__ VT, const float* __restrict__ mb,
                bh* __restrict__ O) {
    constexpr int KVB = 32, NT = SS / KVB;       // 64 tiles
    constexpr float CSC = 0.18033688f;           // 0.125 * log2(e)
    __shared__ __align__(16) bh Ks[2][KVB * 64]; // 2 x 4 KB [key][dk]
    __shared__ __align__(16) bh Vs[2][64 * KVB]; // 2 x 4 KB [dk][key]
    __shared__ __align__(16) bh Plds[4][16 * 40];// 4 x 1.25 KB (row stride 80 B)

    const int tid = threadIdx.x;
    const int w = tid >> 6, lane = tid & 63;
    const int l15 = lane & 15, l4 = lane >> 4;

    const int i = (int)blockIdx.x;
    const int xcd = i & 7, j = i >> 3;           // j 0..127
    const int g = xcd * 4 + (j >> 5);            // (b,h) group 0..31
    const int qt = j & 31;
    const int h = g & 7, b = g >> 3;

    const int q0 = qt * 64 + w * 16;

    // Q fragments (B-operand): lane holds Q[q=q0+l15][dk = ks*32 + l4*8 ..]
    const bh* qp = Q + (size_t)(b * SS + q0 + l15) * DD + h * 64 + l4 * 8;
    const bf16x8 qf0 = *(const bf16x8*)qp;
    const bf16x8 qf1 = *(const bf16x8*)(qp + 32);

    f32x4 ctx[4] = {};
    f32x4 accl = {};
    float m2 = -3e38f;

    bf16x8 ones;
    #pragma unroll
    for (int z = 0; z < 8; ++z) ones[z] = (bh)1.0f;

    // staging geometry: K tile = 32 rows x 128B = 4KB (1 gload/wave);
    // V tile = 64 rows x 64B = 4KB (1 gload/wave)
    const int ksr = lane >> 3;                   // K row-in-8
    const int kcb = (lane & 7) ^ ksr;            // K src 16B slot (xor row&7)
    const int vrow = lane >> 2;                  // V row-in-16
    const int vcb  = (lane & 3) ^ (vrow & 3);    // V src 16B slot (xor row&3)

    const bh* kg = K + ((size_t)(b * SS) + w * 8 + ksr) * DD + h * 64 + 8 * kcb;
    const bh* vg = VT + ((size_t)((b * HH + h) * 64) + w * 16 + vrow) * SS + 8 * vcb;
    const float* mbb = mb + (size_t)b * SS + l4 * 4;

    auto stage = [&](int buf, int kt) {
        gload_lds16(kg + (size_t)kt * DD, &Ks[buf][w * 512]);
        gload_lds16(vg + kt,              &Vs[buf][w * 512]);
    };

    f32x4 mbc[2];
    stage(0, 0);
    mbc[0] = *(const f32x4*)(mbb);
    mbc[1] = *(const f32x4*)(mbb + 16);
    __syncthreads();

    for (int t = 0; t < NT; ++t) {
        const int buf = t & 1;
        const int kt = t * KVB;
        if (t > 0) { WAITVM(2); __builtin_amdgcn_s_barrier(); }
        if (t + 1 < NT) stage(buf ^ 1, kt + KVB);

        // ---- QK^T (swapped): sc[nf] = D[key][q=l15], keys nf*16 + l4*4 + r ----
        const char* Kb = (const char*)&Ks[buf][0];
        bf16x8 kf[2][2];
        #pragma unroll
        for (int ks = 0; ks < 2; ++ks)
            #pragma unroll
            for (int nf = 0; nf < 2; ++nf) {
                const int row = nf * 16 + l15;
                kf[ks][nf] = *(const bf16x8*)(Kb + row * 128 +
                              ((ks * 64 + l4 * 16) ^ ((row & 7) << 4)));
            }
        f32x4 sc[2] = {};
        __builtin_amdgcn_s_setprio(1);
        #pragma unroll
        for (int ks = 0; ks < 2; ++ks)
            #pragma unroll
            for (int nf = 0; nf < 2; ++nf)
                sc[nf] = __builtin_amdgcn_mfma_f32_16x16x32_bf16(
                    kf[ks][nf], ks ? qf1 : qf0, sc[nf], 0, 0, 0);
        __builtin_amdgcn_s_setprio(0);

        // ---- z = qk*c + bias (log2 domain); per-lane max; defer-max check ----
        float tm = -3e38f;
        #pragma unroll
        for (int nf = 0; nf < 2; ++nf)
            #pragma unroll
            for (int r = 0; r < 4; ++r) {
                const float z = fmaf(sc[nf][r], CSC, mbc[nf][r]);
                sc[nf][r] = z;
                tm = fmaxf(tm, z);
            }
        if (__any(tm > m2 + 11.5f)) {            // rare after warm-up
            tm = fmaxf(tm, __shfl_xor(tm, 16, 64));
            tm = fmaxf(tm, __shfl_xor(tm, 32, 64));
            const float mn = fmaxf(fmaxf(tm, m2), -60.f);
            const float fac = __builtin_amdgcn_exp2f(m2 - mn);
            m2 = mn;
            accl *= fac;
            #pragma unroll
            for (int nf = 0; nf < 4; ++nf)
                #pragma unroll
                for (int r = 0; r < 4; ++r)
                    ctx[nf][r] *= fac;
        }

        // ---- P = exp2(z - m2) -> LDS row q=l15 (stride 80B) ----
        char* Pw = (char*)&Plds[w][0] + l15 * 80;
        #pragma unroll
        for (int nf = 0; nf < 2; ++nf) {
            union { bh h4[4]; uint64_t u; } pk;
            #pragma unroll
            for (int r = 0; r < 4; ++r)
                pk.h4[r] = (bh)__builtin_amdgcn_exp2f(sc[nf][r] - m2);
            *(uint64_t*)(Pw + nf * 32 + l4 * 8) = pk.u;
        }
        WAITLGKM0;
        const bf16x8 pa = *(const bf16x8*)(Pw + l4 * 16);

        // ---- PV (swapped): ctx[nf] = D[dk][q=l15]; lrun via ones-MFMA ----
        const char* Vb = (const char*)&Vs[buf][0];
        bf16x8 vf[4];
        #pragma unroll
        for (int nf = 0; nf < 4; ++nf) {
            const int row = nf * 16 + l15;
            vf[nf] = *(const bf16x8*)(Vb + row * 64 + ((l4 ^ (l15 & 3)) << 4));
        }
        __builtin_amdgcn_s_setprio(1);
        #pragma unroll
        for (int nf = 0; nf < 4; ++nf)
            ctx[nf] = __builtin_amdgcn_mfma_f32_16x16x32_bf16(vf[nf], pa, ctx[nf], 0, 0, 0);
        accl = __builtin_amdgcn_mfma_f32_16x16x32_bf16(ones, pa, accl, 0, 0, 0);
        __builtin_amdgcn_s_setprio(0);

        if (t + 1 < NT) {                        // mask bias for t+1
            mbc[0] = *(const f32x4*)(mbb + kt + KVB);
            mbc[1] = *(const f32x4*)(mbb + kt + KVB + 16);
        }
    }

    // ---- epilogue: q = l15, dk = nf*16 + l4*4 + r ----
    const float linv = 1.0f / accl[0];
    #pragma unroll
    for (int nf = 0; nf < 4; ++nf) {
        union { bh h4[4]; uint64_t u; } pk;
        #pragma unroll
        for (int r = 0; r < 4; ++r)
            pk.h4[r] = (bh)(ctx[nf][r] * linv);
        *(uint64_t*)(O + (size_t)(b * SS + q0 + l15) * DD +
                     h * 64 + nf * 16 + l4 * 4) = pk.u;
    }
}

// ---------------- host launch ----------------
extern "C" void kernel_launch(void* const* d_in, const int* in_sizes, int n_in,
                              void* d_out, int out_size, void* d_ws, size_t ws_size,
                              hipStream_t stream) {
    const int*   seq  = (const int*)  d_in[0];
    const float* mask = (const float*)d_in[1];
    const float* pos  = (const float*)d_in[2];
    const float* emb  = (const float*)d_in[3];
    const float* wq = (const float*)d_in[4];  const float* bq = (const float*)d_in[5];
    const float* wk = (const float*)d_in[6];  const float* bk = (const float*)d_in[7];
    const float* wv = (const float*)d_in[8];  const float* bv = (const float*)d_in[9];
    const float* wo = (const float*)d_in[10]; const float* bo = (const float*)d_in[11];
    const float* ag = (const float*)d_in[12]; const float* ab = (const float*)d_in[13];
    const float* am = (const float*)d_in[14]; const float* av = (const float*)d_in[15];
    const float* d1w = (const float*)d_in[16]; const float* d1b = (const float*)d_in[17];
    const float* d2w = (const float*)d_in[18]; const float* d2b = (const float*)d_in[19];
    const float* fg = (const float*)d_in[20]; const float* fb = (const float*)d_in[21];
    const float* fm = (const float*)d_in[22]; const float* fv = (const float*)d_in[23];

    float* X = (float*)d_out;

    char* p = (char*)d_ws;
    auto take = [&](size_t n) { char* q = p; p += (n + 255) & ~(size_t)255; return q; };
    const size_t WE  = (size_t)LL * DD * DD;          // per-matrix weight elems
    const size_t WQE = (size_t)LL * 3 * DD * DD;      // fused QKV elems
    bh* wcat = (bh*)take(WQE * 2);
    bh* wot = (bh*)take(WE * 2);
    bh* w1t = (bh*)take(WE * 2);
    bh* w2t = (bh*)take(WE * 2);
    const size_t AE = (size_t)NTOK * DD;
    bh* xb   = (bh*)take(AE * 2);
    bh* qb   = (bh*)take(AE * 2);
    bh* kb   = (bh*)take(AE * 2);
    bh* ctxb = (bh*)take(AE * 2);
    bh* subb = (bh*)take(AE * 2);
    bh* h1b  = (bh*)take(AE * 2);
    bh* vT   = (bh*)take(AE * 2);
    float* mbias = (float*)take((size_t)BB * SS * 4);

    const int QKV_OS = 3 * DD * DD;                   // 1536*512 per layer
    const dim3 wg(16, 16, LL), wb(32, 8);
    wprep<<<wg, wb, 0, stream>>>(wq,  wcat + 0 * DD * DD, QKV_OS);
    wprep<<<wg, wb, 0, stream>>>(wk,  wcat + 1 * DD * DD, QKV_OS);
    wprep<<<wg, wb, 0, stream>>>(wv,  wcat + 2 * DD * DD, QKV_OS);
    wprep<<<wg, wb, 0, stream>>>(wo,  wot, DD * DD);
    wprep<<<wg, wb, 0, stream>>>(d1w, w1t, DD * DD);
    wprep<<<wg, wb, 0, stream>>>(d2w, w2t, DD * DD);

    maskprep<<<dim3(BB * SS / 1024), dim3(256), 0, stream>>>(mask, mbias);
    embed_k<<<dim3(NTOK), dim3(128), 0, stream>>>(seq, emb, pos, xb);

    for (int l = 0; l < LL; ++l) {
        const size_t wof = (size_t)l * DD * DD;
        const int    bof = l * DD;
        gemm_qkv<<<dim3(1536), dim3(256), 0, stream>>>(
            xb, wcat + (size_t)l * QKV_OS, bq + bof, bk + bof, bv + bof, qb, kb, vT);
        flash_attn<<<dim3(1024), dim3(256), 0, stream>>>(qb, kb, vT, mbias, ctxb);
        gemm64<1, false><<<dim3(1024), dim3(256), 0, stream>>>(
            ctxb, wot + wof, bo + bof, subb, xb, nullptr,
            ag + bof, ab + bof, am + bof, av + bof);
        gemm64<2, false><<<dim3(1024), dim3(256), 0, stream>>>(
            subb, w1t + wof, d1b + bof, h1b, nullptr, nullptr,
            nullptr, nullptr, nullptr, nullptr);
        if (l + 1 < LL) {
            gemm64<1, false><<<dim3(1024), dim3(256), 0, stream>>>(
                h1b, w2t + wof, d2b + bof, xb, subb, nullptr,
                fg + bof, fb + bof, fm + bof, fv + bof);
        } else {
            gemm64<1, true><<<dim3(1024), dim3(256), 0, stream>>>(
                h1b, w2t + wof, d2b + bof, xb, subb, X,
                fg + bof, fb + bof, fm + bof, fv + bof);
        }
    }
}